// Round 9
// baseline (961.242 us; speedup 1.0000x reference)
//
#include <hip/hip_runtime.h>
#include <math.h>

#define NA 30000
#define NB 100000
#define NHALF 50000
#define NANG 200000
#define DD 128
#define HH 256
#define LL 8

typedef unsigned short ushort_t;
typedef unsigned int uint_t;
typedef short s16x8 __attribute__((ext_vector_type(8)));
typedef float f32x4 __attribute__((ext_vector_type(4)));

__device__ __forceinline__ ushort_t f2bf(float x) {
    unsigned int u = __builtin_bit_cast(unsigned int, x);
    u += 0x7fff + ((u >> 16) & 1);
    return (ushort_t)(u >> 16);
}
__device__ __forceinline__ float bf2f(ushort_t b) {
    unsigned int u = ((unsigned int)b) << 16;
    return __builtin_bit_cast(float, u);
}

// ---------------- node init (fp32 + bf16 shadow)
__global__ __launch_bounds__(256) void k_node_init(
    const int* __restrict__ cat, const float* __restrict__ emb,
    float* __restrict__ node, ushort_t* __restrict__ node_bf)
{
    int tid = threadIdx.x;
    int r = blockIdx.x * 2 + (tid >> 7);
    int c = tid & 127;
    const int* cr = cat + r * 9;
    float v = 0.f;
    #pragma unroll
    for (int i = 0; i < 9; ++i) v += emb[((i << 6) + cr[i]) * DD + c];
    node[(size_t)r * DD + c] = v;
    node_bf[(size_t)r * DD + c] = f2bf(v);
}

// ================= CSR build =================
__global__ __launch_bounds__(256) void k_hist2(
    const int* __restrict__ ab_dst, int* __restrict__ cur_ab,
    const int* __restrict__ ba_dst, int* __restrict__ cur_ba)
{
    int i = blockIdx.x * 256 + threadIdx.x;
    if (i < NB) atomicAdd(&cur_ab[ab_dst[i]], 1);
    int j = i - NB;
    if (j >= 0 && j < NANG) atomicAdd(&cur_ba[ba_dst[j]], 1);
}

__global__ __launch_bounds__(1024) void k_scan(
    int* __restrict__ cur_ab, int* __restrict__ rp_ab,
    int* __restrict__ cur_ba, int* __restrict__ rp_ba)
{
    int N; int* cur; int* rp;
    if (blockIdx.x == 0) { cur = cur_ab; rp = rp_ab; N = NA; }
    else                 { cur = cur_ba; rp = rp_ba; N = NHALF; }
    __shared__ int sw[16];
    __shared__ int scarry;
    int tid = threadIdx.x;
    int wid = tid >> 6, lane = tid & 63;
    if (tid == 0) scarry = 0;
    __syncthreads();
    for (int base = 0; base < N; base += 1024) {
        int idx = base + tid;
        int x = (idx < N) ? cur[idx] : 0;
        int v = x;
        #pragma unroll
        for (int off = 1; off < 64; off <<= 1) {
            int t = __shfl_up(v, off);
            if (lane >= off) v += t;
        }
        if (lane == 63) sw[wid] = v;
        __syncthreads();
        if (wid == 0) {
            int wv = (lane < 16) ? sw[lane] : 0;
            #pragma unroll
            for (int off = 1; off < 16; off <<= 1) {
                int t = __shfl_up(wv, off);
                if (lane >= off) wv += t;
            }
            if (lane < 16) sw[lane] = wv;
        }
        __syncthreads();
        int wpre = (wid > 0) ? sw[wid - 1] : 0;
        int carry = scarry;
        int ex = carry + wpre + v - x;
        if (idx < N) { rp[idx] = ex; cur[idx] = ex; }
        __syncthreads();
        if (tid == 1023) scarry = carry + sw[15];
        __syncthreads();
    }
    if (tid == 0) rp[N] = scarry;
}

__global__ __launch_bounds__(256) void k_fill_ab(
    const int* __restrict__ src, const int* __restrict__ dst,
    int* __restrict__ cur, int* __restrict__ psrc, int* __restrict__ peid)
{
    int i = blockIdx.x * 256 + threadIdx.x;
    if (i < NB) {
        int p = atomicAdd(&cur[dst[i]], 1);
        psrc[p] = src[i];
        peid[p] = i;
    }
}

__global__ __launch_bounds__(256) void k_fill_ba(
    const int* __restrict__ src, const int* __restrict__ dst,
    const float* __restrict__ ang,
    int* __restrict__ cur, int* __restrict__ psrc, float* __restrict__ pang)
{
    int i = blockIdx.x * 256 + threadIdx.x;
    if (i < NANG) {
        int p = atomicAdd(&cur[dst[i]], 1);
        psrc[p] = src[i];
        pang[p] = ang[i];
    }
}

// ================= feature builders (A-frag tiled output) =================
__global__ __launch_bounds__(256) void k_feat_ba(
    const int* __restrict__ rp, const int* __restrict__ psrc,
    const float* __restrict__ pang, const float* __restrict__ bfloat,
    const int* __restrict__ bcat,
    ushort_t* __restrict__ aext_t, ushort_t* __restrict__ f_t)
{
    __shared__ float sf[4][16][132];
    int tid = threadIdx.x, wid = tid >> 6, lane = tid & 63;
    int g0 = blockIdx.x * 64 + wid * 16;
    for (int r = 0; r < 16; ++r) {
        int n = g0 + r;
        float v0 = 0.f, v1 = 0.f;
        if (n < NHALF) {
            int p0 = rp[n], p1 = rp[n + 1];
            for (int pb = p0; pb < p1; pb += 64) {
                int cnt = min(p1 - pb, 64);
                int cp = 0; float bv = 0.f, av = 0.f;
                if (lane < cnt) {
                    int s = psrc[pb + lane];
                    cp = (bcat[6 * s] & 15) | ((bcat[6 * s + 1] & 15) << 4) | ((bcat[6 * s + 2] & 15) << 8);
                    bv = bfloat[2 * s];
                    av = pang[pb + lane];
                }
                for (int i = 0; i < cnt; ++i) {
                    int cpi = __shfl(cp, i);
                    float bvi = __shfl(bv, i), avi = __shfl(av, i);
                    if (lane < 48) {
                        v0 += (((cpi >> ((lane >> 4) << 2)) & 15) == (lane & 15)) ? 1.f : 0.f;
                    } else {
                        float d = bvi - 0.1f * (float)(lane - 48);
                        v0 += expf(-10.f * d * d);
                    }
                    if (lane < 4) { float d = bvi - 0.1f * (float)(lane + 16); v1 += expf(-10.f * d * d); }
                    else if (lane < 36) { float d = avi - 0.1f * (float)(lane - 4); v1 += expf(-10.f * d * d); }
                    else if (lane == 36) v1 += 1.f;
                }
            }
        }
        sf[wid][r][lane] = v0;
        sf[wid][r][64 + lane] = v1;
    }
    __syncthreads();
    {
        int ar = lane & 15, aq = (lane >> 4) << 3;
        #pragma unroll
        for (int s = 0; s < 4; ++s) {
            const float* src = &sf[wid][ar][s * 32 + aq];
            uint_t pk[4];
            #pragma unroll
            for (int j = 0; j < 4; ++j)
                pk[j] = (uint_t)f2bf(src[2 * j]) | ((uint_t)f2bf(src[2 * j + 1]) << 16);
            *(uint4*)(aext_t + ((((size_t)blockIdx.x * 4 + wid) * 4 + s) * 64 + lane) * 8) =
                make_uint4(pk[0], pk[1], pk[2], pk[3]);
        }
    }
    __syncthreads();
    for (int r = 0; r < 16; ++r) {
        int n = g0 + r;
        float v0 = 0.f, v1 = 0.f;
        if (n < NHALF) {
            if (lane < 48) {
                v0 = (bcat[6 * n + (lane >> 4)] == (lane & 15)) ? 1.f : 0.f;
            } else {
                float d = bfloat[2 * n] - 0.1f * (float)(lane - 48);
                v0 = expf(-10.f * d * d);
            }
            if (lane < 4) { float d = bfloat[2 * n] - 0.1f * (float)(lane + 16); v1 = expf(-10.f * d * d); }
            else if (lane == 4) v1 = 1.f;
        }
        sf[wid][r][lane] = v0;
        sf[wid][r][64 + lane] = v1;
    }
    __syncthreads();
    {
        int ar = lane & 15, aq = (lane >> 4) << 3;
        #pragma unroll
        for (int s = 0; s < 3; ++s) {
            const float* src = &sf[wid][ar][s * 32 + aq];
            uint_t pk[4];
            #pragma unroll
            for (int j = 0; j < 4; ++j)
                pk[j] = (uint_t)f2bf(src[2 * j]) | ((uint_t)f2bf(src[2 * j + 1]) << 16);
            *(uint4*)(f_t + ((((size_t)blockIdx.x * 4 + wid) * 3 + s) * 64 + lane) * 8) =
                make_uint4(pk[0], pk[1], pk[2], pk[3]);
        }
    }
}

__global__ __launch_bounds__(256) void k_feat_ab(
    const int* __restrict__ rp, const int* __restrict__ peid,
    const float* __restrict__ bfloat, const int* __restrict__ bcat,
    ushort_t* __restrict__ fab_t)
{
    __shared__ float sf[4][16][132];
    int tid = threadIdx.x, wid = tid >> 6, lane = tid & 63;
    int g0 = blockIdx.x * 64 + wid * 16;
    for (int r = 0; r < 16; ++r) {
        int n = g0 + r;
        float v0 = 0.f, v1 = 0.f;
        if (n < NA) {
            int p0 = rp[n], p1 = rp[n + 1];
            for (int pb = p0; pb < p1; pb += 64) {
                int cnt = min(p1 - pb, 64);
                int cp = 0; float bv = 0.f;
                if (lane < cnt) {
                    int e = peid[pb + lane];
                    cp = (bcat[3 * e] & 15) | ((bcat[3 * e + 1] & 15) << 4) | ((bcat[3 * e + 2] & 15) << 8);
                    bv = bfloat[e];
                }
                for (int i = 0; i < cnt; ++i) {
                    int cpi = __shfl(cp, i);
                    float bvi = __shfl(bv, i);
                    if (lane < 48) {
                        v0 += (((cpi >> ((lane >> 4) << 2)) & 15) == (lane & 15)) ? 1.f : 0.f;
                    } else {
                        float d = bvi - 0.1f * (float)(lane - 48);
                        v0 += expf(-10.f * d * d);
                    }
                    if (lane < 4) { float d = bvi - 0.1f * (float)(lane + 16); v1 += expf(-10.f * d * d); }
                    else if (lane == 4) v1 += 1.f;
                }
            }
        }
        sf[wid][r][lane] = v0;
        sf[wid][r][64 + lane] = v1;
    }
    __syncthreads();
    int ar = lane & 15, aq = (lane >> 4) << 3;
    #pragma unroll
    for (int s = 0; s < 3; ++s) {
        const float* src = &sf[wid][ar][s * 32 + aq];
        uint_t pk[4];
        #pragma unroll
        for (int j = 0; j < 4; ++j)
            pk[j] = (uint_t)f2bf(src[2 * j]) | ((uint_t)f2bf(src[2 * j + 1]) << 16);
        *(uint4*)(fab_t + ((((size_t)blockIdx.x * 4 + wid) * 3 + s) * 64 + lane) * 8) =
            make_uint4(pk[0], pk[1], pk[2], pk[3]);
    }
}

// ================= weight folds (fp32) =================
__global__ __launch_bounds__(256) void k_fold(
    const float* __restrict__ ba_w1, const float* __restrict__ lbemb,
    const float* __restrict__ rwb, const float* __restrict__ rbvb,
    const float* __restrict__ rwa, const float* __restrict__ rbva,
    const float* __restrict__ ab_w1, const float* __restrict__ bei,
    const float* __restrict__ brw, const float* __restrict__ brb,
    float* __restrict__ W1ext, float* __restrict__ W1ab0x)
{
    int f = blockIdx.x * 256 + threadIdx.x;
    if (f < 262144) {
        int n = f & 255, k = (f >> 8) & 127, l = f >> 15;
        float v = 0.f;
        if (k <= 100) {
            const float* w1 = ba_w1 + (size_t)l * 32768 + n;
            if (k == 100) {
                const float* r1 = rbvb + (size_t)l * 128;
                const float* r2 = rbva + (size_t)l * 128;
                for (int c = 0; c < 128; ++c) v += (r1[c] + r2[c]) * w1[(size_t)c * 256];
            } else {
                const float* row = (k < 48) ? lbemb + ((size_t)l * 48 + k) * 128
                                 : (k < 68) ? rwb + ((size_t)l * 20 + (k - 48)) * 128
                                            : rwa + ((size_t)l * 32 + (k - 68)) * 128;
                for (int c = 0; c < 128; ++c) v += row[c] * w1[(size_t)c * 256];
            }
        }
        W1ext[f] = v;
    } else if (f < 286720) {
        int f2 = f - 262144;
        int n = f2 & 255, k = f2 >> 8;
        float v = 0.f;
        if (k <= 68) {
            const float* w1 = ab_w1 + n;
            const float* row = (k < 48) ? bei + (size_t)k * 128
                             : (k < 68) ? brw + (size_t)(k - 48) * 128
                                        : brb;
            for (int c = 0; c < 128; ++c) v += row[c] * w1[(size_t)c * 256];
        }
        W1ab0x[f2] = v;
    }
}

// ================= pack weights into B-frag order =================
// regions (frag units): [0,7168) W1ab0 K224; [7168,35840) ab_w1 l1-7;
// [35840,68608) W1ext_ba; [68608,134144) w2 ab+ba; [134144,146432) G
__global__ __launch_bounds__(256) void k_pack(
    const float* __restrict__ ab_w1, const float* __restrict__ W1ab0x,
    const float* __restrict__ W1ext, const float* __restrict__ ab_w2,
    const float* __restrict__ ba_w2, const float* __restrict__ lbemb,
    const float* __restrict__ rwb, const float* __restrict__ rbvb,
    ushort_t* __restrict__ wp)
{
    int f = blockIdx.x * 256 + threadIdx.x;
    if (f >= 146432) return;
    int lane = f & 63;
    int k0 = 0, n = 0, N = 256;
    const float* W = nullptr;
    float vals[8];
    if (f < 7168) {
        int ts = f >> 6; int s = ts % 7, t = ts / 7;
        k0 = s * 32 + ((lane >> 4) << 3); n = t * 16 + (lane & 15); N = 256;
        if (k0 < 128) W = ab_w1;
        else { W = W1ab0x; k0 -= 128; }
    } else if (f < 35840) {
        int f2 = f - 7168; int ts = f2 >> 6;
        int s = ts & 3, t = (ts >> 2) & 15, l = (ts >> 6) + 1;
        W = ab_w1 + (size_t)l * 32768; N = 256;
        k0 = s * 32 + ((lane >> 4) << 3); n = t * 16 + (lane & 15);
    } else if (f < 68608) {
        int f2 = f - 35840; int ts = f2 >> 6;
        int s = ts & 3, t = (ts >> 2) & 15, l = ts >> 6;
        W = W1ext + (size_t)l * 32768; N = 256;
        k0 = s * 32 + ((lane >> 4) << 3); n = t * 16 + (lane & 15);
    } else if (f < 134144) {
        int f2 = f - 68608; int ts = f2 >> 6;
        int s = ts & 7, t = (ts >> 3) & 7, l = (ts >> 6) & 7, grp = ts >> 9;
        W = (grp ? ba_w2 : ab_w2) + (size_t)l * 32768; N = 128;
        k0 = s * 32 + ((lane >> 4) << 3); n = t * 16 + (lane & 15);
    } else {
        int f2 = f - 134144; int ts = f2 >> 6;
        int s = ts % 3, t = (ts / 3) & 7, l = ts / 24;
        N = 128; k0 = s * 32 + ((lane >> 4) << 3); n = t * 16 + (lane & 15);
        #pragma unroll
        for (int j = 0; j < 8; ++j) {
            int k = k0 + j; float v;
            if (k < 48) v = lbemb[(size_t)l * 6144 + (size_t)k * 128 + n];
            else if (k < 68) v = rwb[(size_t)l * 2560 + (size_t)(k - 48) * 128 + n];
            else if (k == 68) v = rbvb[(size_t)l * 128 + n];
            else v = 0.f;
            vals[j] = v;
        }
    }
    if (W) {
        #pragma unroll
        for (int j = 0; j < 8; ++j) vals[j] = W[(size_t)(k0 + j) * N + n];
    }
    uint_t pk[4];
    #pragma unroll
    for (int j = 0; j < 4; ++j)
        pk[j] = (uint_t)f2bf(vals[2 * j]) | ((uint_t)f2bf(vals[2 * j + 1]) << 16);
    *(uint4*)(wp + (size_t)f * 8) = make_uint4(pk[0], pk[1], pk[2], pk[3]);
}

// ================= batched ba MLP — H split in two halves, 17.4KB LDS, no barrier =====
// each wave uses only its own sC1 slice; c2 accumulates frags s=0..3 then 4..7
// per accumulator (same order as the monolithic loop) -> bitwise identical
__global__ __launch_bounds__(256) void k_ba_batch(
    const ushort_t* __restrict__ aext_t, const ushort_t* __restrict__ f_t,
    const ushort_t* __restrict__ wp,
    const float* __restrict__ ba_b1, const float* __restrict__ ba_b2,
    const float* __restrict__ ba_g, const float* __restrict__ ba_bt,
    ushort_t* __restrict__ pool, float* __restrict__ edge_out,
    int lbase, float inv_sqrt_n)
{
    __shared__ ushort_t sC1[4][16 * 136];
    int tid = threadIdx.x, wid = tid >> 6, lane = tid & 63;
    int l = lbase + (blockIdx.x & 3);
    int rb = blockIdx.x >> 2;
    const ushort_t* w1p = wp + ((size_t)35840 + (size_t)l * 4096) * 8;
    const ushort_t* w2p = wp + ((size_t)68608 + (size_t)(8 + l) * 4096) * 8;
    const ushort_t* gp  = wp + ((size_t)134144 + (size_t)l * 1536) * 8;
    const float* b1 = ba_b1 + l * HH;
    const float* b2 = ba_b2 + l * DD;
    const float* g  = ba_g + l * DD;
    const float* bt = ba_bt + l * DD;
    ushort_t* outb = pool + (size_t)(l & 3) * NHALF * DD;

    int arow = lane & 15, aq = (lane >> 4) << 3;
    int colb = lane & 15;
    int r0 = (lane >> 4) << 2;

    s16x8 af[4];
    #pragma unroll
    for (int s = 0; s < 4; ++s)
        af[s] = *(const s16x8*)(aext_t + ((((size_t)rb * 4 + wid) * 4 + s) * 64 + lane) * 8);

    f32x4 c2[8];
    #pragma unroll
    for (int t = 0; t < 8; ++t) c2[t] = (f32x4){0.f, 0.f, 0.f, 0.f};

    #pragma unroll
    for (int half = 0; half < 2; ++half) {
        for (int tt = 0; tt < 8; ++tt) {
            int t = half * 8 + tt;
            f32x4 acc = {0.f, 0.f, 0.f, 0.f};
            #pragma unroll
            for (int s = 0; s < 4; ++s) {
                s16x8 bf = *(const s16x8*)(w1p + ((size_t)(t * 4 + s) * 64 + lane) * 8);
                acc = __builtin_amdgcn_mfma_f32_16x16x32_bf16(af[s], bf, acc, 0, 0, 0);
            }
            float b1v = b1[t * 16 + colb];
            #pragma unroll
            for (int r = 0; r < 4; ++r)
                sC1[wid][(r0 + r) * 136 + tt * 16 + colb] = f2bf(fmaxf(acc[r] + b1v, 0.f));
        }
        s16x8 a2h[4];
        #pragma unroll
        for (int s = 0; s < 4; ++s)
            a2h[s] = *(const s16x8*)&sC1[wid][arow * 136 + s * 32 + aq];
        for (int t = 0; t < 8; ++t) {
            #pragma unroll
            for (int s = 0; s < 4; ++s) {
                s16x8 bf = *(const s16x8*)(w2p + ((size_t)(t * 8 + half * 4 + s) * 64 + lane) * 8);
                c2[t] = __builtin_amdgcn_mfma_f32_16x16x32_bf16(a2h[s], bf, c2[t], 0, 0, 0);
            }
        }
    }

    s16x8 af3[3];
    #pragma unroll
    for (int s = 0; s < 3; ++s)
        af3[s] = *(const s16x8*)(f_t + ((((size_t)rb * 4 + wid) * 3 + s) * 64 + lane) * 8);

    {
        float b2v[8];
        #pragma unroll
        for (int t = 0; t < 8; ++t) b2v[t] = b2[t * 16 + colb];
        #pragma unroll
        for (int t = 0; t < 8; ++t)
            #pragma unroll
            for (int r = 0; r < 4; ++r) c2[t][r] += b2v[t];
    }
    float mu4[4], rs4[4];
    #pragma unroll
    for (int r = 0; r < 4; ++r) {
        float s = 0.f, ss = 0.f;
        #pragma unroll
        for (int t = 0; t < 8; ++t) { float x = c2[t][r]; s += x; ss += x * x; }
        #pragma unroll
        for (int m = 1; m < 16; m <<= 1) {
            s  += __shfl_xor(s, m);
            ss += __shfl_xor(ss, m);
        }
        float mu = s * (1.f / 128.f);
        float var = ss * (1.f / 128.f) - mu * mu;
        mu4[r] = mu;
        rs4[r] = rsqrtf(var + 1e-5f);
    }
    int growb = rb * 64 + wid * 16 + r0;
    #pragma unroll
    for (int t = 0; t < 8; ++t) {
        f32x4 racc = {0.f, 0.f, 0.f, 0.f};
        #pragma unroll
        for (int s = 0; s < 3; ++s) {
            s16x8 bf = *(const s16x8*)(gp + ((size_t)(t * 3 + s) * 64 + lane) * 8);
            racc = __builtin_amdgcn_mfma_f32_16x16x32_bf16(af3[s], bf, racc, 0, 0, 0);
        }
        int n = t * 16 + colb;
        float gv = g[n], btv = bt[n];
        #pragma unroll
        for (int r = 0; r < 4; ++r) {
            int grow = growb + r;
            if (grow < NHALF) {
                float y = (c2[t][r] - mu4[r]) * rs4[r] * gv + btv;
                float o = fmaxf(y * inv_sqrt_n, 0.f) + racc[r];
                if (l < 7) {
                    outb[(size_t)grow * DD + n] = f2bf(o);
                } else {
                    edge_out[(size_t)(2 * grow) * DD + n] = o;
                    edge_out[(size_t)(2 * grow + 1) * DD + n] = o;
                }
            }
        }
    }
}

// ================= standalone gather: one wave per dst row =================
template<bool L0>
__global__ __launch_bounds__(256) void k_gather(
    const uint_t* __restrict__ node2, const uint_t* __restrict__ half2,
    const int* __restrict__ rp, const int* __restrict__ psrc,
    const int* __restrict__ peid, uint_t* __restrict__ agg)
{
    int wid = threadIdx.x >> 6, lane = threadIdx.x & 63;
    int n = blockIdx.x * 4 + wid;
    if (n >= 30016) return;
    float v0 = 0.f, v1 = 0.f;
    if (n < NA) {
        int p0 = rp[n], p1 = rp[n + 1];
        for (int pb = p0; pb < p1; pb += 64) {
            int cnt = min(p1 - pb, 64);
            int sv = 0, ev = 0;
            if (lane < cnt) {
                sv = psrc[pb + lane];
                if (!L0) ev = peid[pb + lane] >> 1;
            }
            for (int i = 0; i < cnt; i += 4) {
                bool c1 = (i + 1 < cnt), c2m = (i + 2 < cnt), c3 = (i + 3 < cnt);
                int s0 = __shfl(sv, i);
                int s1 = __shfl(sv, c1 ? i + 1 : i);
                int s2 = __shfl(sv, c2m ? i + 2 : i);
                int s3 = __shfl(sv, c3 ? i + 3 : i);
                uint_t a0 = node2[(size_t)s0 * 64 + lane];
                uint_t a1 = node2[(size_t)s1 * 64 + lane];
                uint_t a2 = node2[(size_t)s2 * 64 + lane];
                uint_t a3 = node2[(size_t)s3 * 64 + lane];
                uint_t h0 = 0, h1 = 0, h2 = 0, h3 = 0;
                if (!L0) {
                    int e0 = __shfl(ev, i);
                    int e1 = __shfl(ev, c1 ? i + 1 : i);
                    int e2 = __shfl(ev, c2m ? i + 2 : i);
                    int e3 = __shfl(ev, c3 ? i + 3 : i);
                    h0 = half2[(size_t)e0 * 64 + lane];
                    h1 = half2[(size_t)e1 * 64 + lane];
                    h2 = half2[(size_t)e2 * 64 + lane];
                    h3 = half2[(size_t)e3 * 64 + lane];
                }
                v0 += bf2f((ushort_t)(a0 & 0xffff));
                v1 += bf2f((ushort_t)(a0 >> 16));
                if (!L0) { v0 += bf2f((ushort_t)(h0 & 0xffff)); v1 += bf2f((ushort_t)(h0 >> 16)); }
                if (c1) {
                    v0 += bf2f((ushort_t)(a1 & 0xffff));
                    v1 += bf2f((ushort_t)(a1 >> 16));
                    if (!L0) { v0 += bf2f((ushort_t)(h1 & 0xffff)); v1 += bf2f((ushort_t)(h1 >> 16)); }
                }
                if (c2m) {
                    v0 += bf2f((ushort_t)(a2 & 0xffff));
                    v1 += bf2f((ushort_t)(a2 >> 16));
                    if (!L0) { v0 += bf2f((ushort_t)(h2 & 0xffff)); v1 += bf2f((ushort_t)(h2 >> 16)); }
                }
                if (c3) {
                    v0 += bf2f((ushort_t)(a3 & 0xffff));
                    v1 += bf2f((ushort_t)(a3 >> 16));
                    if (!L0) { v0 += bf2f((ushort_t)(h3 & 0xffff)); v1 += bf2f((ushort_t)(h3 >> 16)); }
                }
            }
        }
    }
    agg[(size_t)n * 64 + lane] = (uint_t)f2bf(v0) | ((uint_t)f2bf(v1) << 16);
}

// ================= MLP only (ab path) — same two-half split, 17.4KB LDS ==========
template<int KS, bool L0>
__global__ __launch_bounds__(256) void k_mlp_ab(
    const ushort_t* __restrict__ agg, const ushort_t* __restrict__ fab_t,
    const ushort_t* __restrict__ w1p, const float* __restrict__ b1,
    const ushort_t* __restrict__ w2p, const float* __restrict__ b2,
    const float* __restrict__ g, const float* __restrict__ bt,
    const float* __restrict__ resid, float* __restrict__ outf,
    ushort_t* __restrict__ outb, float inv_sqrt_n)
{
    __shared__ ushort_t sC1[4][16 * 136];
    int tid = threadIdx.x, wid = tid >> 6, lane = tid & 63;
    int g0 = blockIdx.x * 64 + wid * 16;

    int arow = lane & 15, aq = (lane >> 4) << 3;
    int colb = lane & 15;
    int r0 = (lane >> 4) << 2;

    s16x8 af[KS];
    #pragma unroll
    for (int s = 0; s < 4; ++s)
        af[s] = *(const s16x8*)(agg + (size_t)(g0 + arow) * 128 + s * 32 + aq);
    if (L0) {
        #pragma unroll
        for (int s = 0; s < 3; ++s)
            af[4 + s] = *(const s16x8*)(fab_t + ((((size_t)blockIdx.x * 4 + wid) * 3 + s) * 64 + lane) * 8);
    }

    f32x4 c2[8];
    #pragma unroll
    for (int t = 0; t < 8; ++t) c2[t] = (f32x4){0.f, 0.f, 0.f, 0.f};

    #pragma unroll
    for (int half = 0; half < 2; ++half) {
        for (int tt = 0; tt < 8; ++tt) {
            int t = half * 8 + tt;
            f32x4 acc = {0.f, 0.f, 0.f, 0.f};
            #pragma unroll
            for (int s = 0; s < KS; ++s) {
                s16x8 bf = *(const s16x8*)(w1p + ((size_t)(t * KS + s) * 64 + lane) * 8);
                acc = __builtin_amdgcn_mfma_f32_16x16x32_bf16(af[s], bf, acc, 0, 0, 0);
            }
            float b1v = b1[t * 16 + colb];
            #pragma unroll
            for (int r = 0; r < 4; ++r)
                sC1[wid][(r0 + r) * 136 + tt * 16 + colb] = f2bf(fmaxf(acc[r] + b1v, 0.f));
        }
        s16x8 a2h[4];
        #pragma unroll
        for (int s = 0; s < 4; ++s)
            a2h[s] = *(const s16x8*)&sC1[wid][arow * 136 + s * 32 + aq];
        for (int t = 0; t < 8; ++t) {
            #pragma unroll
            for (int s = 0; s < 4; ++s) {
                s16x8 bf = *(const s16x8*)(w2p + ((size_t)(t * 8 + half * 4 + s) * 64 + lane) * 8);
                c2[t] = __builtin_amdgcn_mfma_f32_16x16x32_bf16(a2h[s], bf, c2[t], 0, 0, 0);
            }
        }
    }

    float b2v[8], gv[8], btv[8];
    #pragma unroll
    for (int t = 0; t < 8; ++t) {
        int n = t * 16 + colb;
        b2v[t] = b2[n]; gv[t] = g[n]; btv[t] = bt[n];
    }
    #pragma unroll
    for (int t = 0; t < 8; ++t)
        #pragma unroll
        for (int r = 0; r < 4; ++r) c2[t][r] += b2v[t];

    #pragma unroll
    for (int r = 0; r < 4; ++r) {
        float s = 0.f, ss = 0.f;
        #pragma unroll
        for (int t = 0; t < 8; ++t) { float x = c2[t][r]; s += x; ss += x * x; }
        #pragma unroll
        for (int m = 1; m < 16; m <<= 1) {
            s  += __shfl_xor(s, m);
            ss += __shfl_xor(ss, m);
        }
        float mu = s * (1.f / 128.f);
        float var = ss * (1.f / 128.f) - mu * mu;
        float rstd = rsqrtf(var + 1e-5f);
        int grow = g0 + r0 + r;
        if (grow < NA) {
            #pragma unroll
            for (int t = 0; t < 8; ++t) {
                int n = t * 16 + colb;
                float y = (c2[t][r] - mu) * rstd * gv[t] + btv[t];
                float o = fmaxf(y * inv_sqrt_n, 0.f) + resid[(size_t)grow * DD + n];
                outf[(size_t)grow * DD + n] = o;
                outb[(size_t)grow * DD + n] = f2bf(o);
            }
        }
    }
}

// ---------------- graph = node.mean(axis=0)
__global__ __launch_bounds__(256) void k_graph_mean(
    const float* __restrict__ node, float* __restrict__ graph)
{
    int tid = threadIdx.x;
    int c = tid & 127, h = tid >> 7;
    const int rpb = 250;
    int r0 = blockIdx.x * rpb;
    float s = 0.f;
    for (int r = r0 + h; r < r0 + rpb; r += 2) s += node[(size_t)r * DD + c];
    __shared__ float sS[256];
    sS[tid] = s;
    __syncthreads();
    if (tid < 128) atomicAdd(&graph[c], (sS[tid] + sS[tid + 128]) * (1.f / 30000.f));
}

extern "C" void kernel_launch(void* const* d_in, const int* in_sizes, int n_in,
                              void* d_out, int out_size, void* d_ws, size_t ws_size,
                              hipStream_t stream)
{
    const int*   atom_cat         = (const int*)d_in[0];
    const int*   bond_cat         = (const int*)d_in[1];
    const float* bond_float       = (const float*)d_in[2];
    const float* angle_float      = (const float*)d_in[3];
    const int*   ab_src           = (const int*)d_in[4];
    const int*   ab_dst           = (const int*)d_in[5];
    const int*   ba_src           = (const int*)d_in[6];
    const int*   ba_dst           = (const int*)d_in[7];
    const float* atom_emb         = (const float*)d_in[8];
    const float* bond_emb_init    = (const float*)d_in[9];
    const float* bond_rbf_w_init  = (const float*)d_in[10];
    const float* bond_rbf_b_init  = (const float*)d_in[11];
    const float* layer_bond_emb   = (const float*)d_in[12];
    const float* layer_bond_rbf_w = (const float*)d_in[13];
    const float* layer_bond_rbf_b = (const float*)d_in[14];
    const float* layer_angle_rbf_w= (const float*)d_in[15];
    const float* layer_angle_rbf_b= (const float*)d_in[16];
    const float* ab_w1 = (const float*)d_in[17];
    const float* ab_b1 = (const float*)d_in[18];
    const float* ab_w2 = (const float*)d_in[19];
    const float* ab_b2 = (const float*)d_in[20];
    const float* ab_g  = (const float*)d_in[21];
    const float* ab_bt = (const float*)d_in[22];
    const float* ba_w1 = (const float*)d_in[23];
    const float* ba_b1 = (const float*)d_in[24];
    const float* ba_w2 = (const float*)d_in[25];
    const float* ba_b2 = (const float*)d_in[26];
    const float* ba_g  = (const float*)d_in[27];
    const float* ba_bt = (const float*)d_in[28];

    float* node     = (float*)d_out;
    float* edge_out = node + (size_t)NA * DD;
    float* graph    = edge_out + (size_t)NB * DD;

    // ---- ws layout
    ushort_t* nbf0   = (ushort_t*)d_ws;                        // NA*128
    ushort_t* nbf1   = nbf0 + (size_t)NA * DD;                 // NA*128
    ushort_t* pool   = nbf1 + (size_t)NA * DD;                 // 4*NHALF*128
    ushort_t* aext_t = pool + (size_t)4 * NHALF * DD;          // 782*8192
    ushort_t* f_t    = aext_t + (size_t)782 * 8192;            // 782*6144
    ushort_t* fab_t  = f_t + (size_t)782 * 6144;               // 469*6144
    ushort_t* wp     = fab_t + (size_t)469 * 6144;             // 146432*8
    float*    W1ext  = (float*)(wp + (size_t)146432 * 8);      // 262144
    float*    W1ab0x = W1ext + 262144;                         // 24576
    int*      cur_ab = (int*)(W1ab0x + 24576);                 // NA
    int*      cur_ba = cur_ab + NA;                            // NHALF
    int*      rp_ab  = cur_ba + NHALF;                         // NA+1
    int*      rp_ba  = rp_ab + NA + 1;                         // NHALF+1
    int*      psrc_ab= rp_ba + NHALF + 1;                      // NB
    int*      peid_ab= psrc_ab + NB;                           // NB
    int*      psrc_ba= peid_ab + NB;                           // NANG
    float*    pang   = (float*)(psrc_ba + NANG);               // NANG
    uint_t*   agg    = (uint_t*)(pang + NANG);                 // 30016*64

    const float isn_a = (float)(1.0 / sqrt(30000.0));
    const float isn_h = (float)(1.0 / sqrt(50000.0));

    // ---- CSR build
    hipMemsetAsync(cur_ab, 0, (size_t)(NA + NHALF) * sizeof(int), stream);
    k_hist2<<<(NB + NANG + 255) / 256, 256, 0, stream>>>(ab_dst, cur_ab, ba_dst, cur_ba);
    k_scan<<<2, 1024, 0, stream>>>(cur_ab, rp_ab, cur_ba, rp_ba);
    k_fill_ab<<<(NB + 255) / 256, 256, 0, stream>>>(ab_src, ab_dst, cur_ab, psrc_ab, peid_ab);
    k_fill_ba<<<(NANG + 255) / 256, 256, 0, stream>>>(ba_src, ba_dst, angle_float, cur_ba, psrc_ba, pang);

    // ---- features + folds + packing
    k_feat_ba<<<782, 256, 0, stream>>>(rp_ba, psrc_ba, pang, bond_float, bond_cat, aext_t, f_t);
    k_feat_ab<<<469, 256, 0, stream>>>(rp_ab, peid_ab, bond_float, bond_cat, fab_t);
    k_fold<<<1120, 256, 0, stream>>>(ba_w1, layer_bond_emb, layer_bond_rbf_w,
        layer_bond_rbf_b, layer_angle_rbf_w, layer_angle_rbf_b,
        ab_w1, bond_emb_init, bond_rbf_w_init, bond_rbf_b_init, W1ext, W1ab0x);
    k_pack<<<572, 256, 0, stream>>>(ab_w1, W1ab0x, W1ext, ab_w2, ba_w2,
        layer_bond_emb, layer_bond_rbf_w, layer_bond_rbf_b, wp);

    k_node_init<<<NA / 2, 256, 0, stream>>>(atom_cat, atom_emb, node, nbf0);

    // ---- batched ba layers 0-3 -> pool[0..3]
    k_ba_batch<<<782 * 4, 256, 0, stream>>>(aext_t, f_t, wp, ba_b1, ba_b2, ba_g, ba_bt,
        pool, edge_out, 0, isn_h);

    ushort_t* nbf[2] = {nbf0, nbf1};
    for (int l = 0; l < LL; ++l) {
        const uint_t* rd = (const uint_t*)nbf[l & 1];
        ushort_t* wr = nbf[1 - (l & 1)];
        const uint_t* halfbuf = (const uint_t*)(pool + (size_t)((l - 1) & 3) * NHALF * DD);
        const ushort_t* ab_w1p = l ? wp + ((size_t)7168 + (size_t)(l - 1) * 4096) * 8 : wp;
        const ushort_t* ab_w2p = wp + ((size_t)68608 + (size_t)l * 4096) * 8;

        if (l == 0) {
            k_gather<true><<<7504, 256, 0, stream>>>(rd, rd, rp_ab, psrc_ab, peid_ab, agg);
            k_mlp_ab<7, true><<<469, 256, 0, stream>>>(
                (const ushort_t*)agg, fab_t,
                ab_w1p, ab_b1, ab_w2p, ab_b2, ab_g, ab_bt,
                node, node, wr, isn_a);
        } else {
            k_gather<false><<<7504, 256, 0, stream>>>(rd, halfbuf, rp_ab, psrc_ab, peid_ab, agg);
            k_mlp_ab<4, false><<<469, 256, 0, stream>>>(
                (const ushort_t*)agg, fab_t,
                ab_w1p, ab_b1 + l * HH, ab_w2p, ab_b2 + l * DD,
                ab_g + l * DD, ab_bt + l * DD, node, node, wr, isn_a);
        }

        if (l == 3)   // pool[0..2] consumed; refill with layers 4-6 (+edge from 7)
            k_ba_batch<<<782 * 4, 256, 0, stream>>>(aext_t, f_t, wp, ba_b1, ba_b2, ba_g, ba_bt,
                pool, edge_out, 4, isn_h);
    }

    hipMemsetAsync(graph, 0, DD * sizeof(float), stream);
    k_graph_mean<<<120, 256, 0, stream>>>(node, graph);
}

// Round 11
// 796.602 us; speedup vs baseline: 1.2067x; 1.2067x over previous
//
#include <hip/hip_runtime.h>
#include <math.h>

#define NA 30000
#define NB 100000
#define NHALF 50000
#define NANG 200000
#define DD 128
#define HH 256
#define LL 8

typedef unsigned short ushort_t;
typedef unsigned int uint_t;
typedef short s16x8 __attribute__((ext_vector_type(8)));
typedef float f32x4 __attribute__((ext_vector_type(4)));

__device__ __forceinline__ ushort_t f2bf(float x) {
    unsigned int u = __builtin_bit_cast(unsigned int, x);
    u += 0x7fff + ((u >> 16) & 1);
    return (ushort_t)(u >> 16);
}
__device__ __forceinline__ float bf2f(ushort_t b) {
    unsigned int u = ((unsigned int)b) << 16;
    return __builtin_bit_cast(float, u);
}

// ---------------- node init (fp32 + bf16 shadow)
__global__ __launch_bounds__(256) void k_node_init(
    const int* __restrict__ cat, const float* __restrict__ emb,
    float* __restrict__ node, ushort_t* __restrict__ node_bf)
{
    int tid = threadIdx.x;
    int r = blockIdx.x * 2 + (tid >> 7);
    int c = tid & 127;
    const int* cr = cat + r * 9;
    float v = 0.f;
    #pragma unroll
    for (int i = 0; i < 9; ++i) v += emb[((i << 6) + cr[i]) * DD + c];
    node[(size_t)r * DD + c] = v;
    node_bf[(size_t)r * DD + c] = f2bf(v);
}

// ================= CSR build =================
__global__ __launch_bounds__(256) void k_hist2(
    const int* __restrict__ ab_dst, int* __restrict__ cur_ab,
    const int* __restrict__ ba_dst, int* __restrict__ cur_ba)
{
    int i = blockIdx.x * 256 + threadIdx.x;
    if (i < NB) atomicAdd(&cur_ab[ab_dst[i]], 1);
    int j = i - NB;
    if (j >= 0 && j < NANG) atomicAdd(&cur_ba[ba_dst[j]], 1);
}

__global__ __launch_bounds__(1024) void k_scan(
    int* __restrict__ cur_ab, int* __restrict__ rp_ab,
    int* __restrict__ cur_ba, int* __restrict__ rp_ba)
{
    int N; int* cur; int* rp;
    if (blockIdx.x == 0) { cur = cur_ab; rp = rp_ab; N = NA; }
    else                 { cur = cur_ba; rp = rp_ba; N = NHALF; }
    __shared__ int sw[16];
    __shared__ int scarry;
    int tid = threadIdx.x;
    int wid = tid >> 6, lane = tid & 63;
    if (tid == 0) scarry = 0;
    __syncthreads();
    for (int base = 0; base < N; base += 1024) {
        int idx = base + tid;
        int x = (idx < N) ? cur[idx] : 0;
        int v = x;
        #pragma unroll
        for (int off = 1; off < 64; off <<= 1) {
            int t = __shfl_up(v, off);
            if (lane >= off) v += t;
        }
        if (lane == 63) sw[wid] = v;
        __syncthreads();
        if (wid == 0) {
            int wv = (lane < 16) ? sw[lane] : 0;
            #pragma unroll
            for (int off = 1; off < 16; off <<= 1) {
                int t = __shfl_up(wv, off);
                if (lane >= off) wv += t;
            }
            if (lane < 16) sw[lane] = wv;
        }
        __syncthreads();
        int wpre = (wid > 0) ? sw[wid - 1] : 0;
        int carry = scarry;
        int ex = carry + wpre + v - x;
        if (idx < N) { rp[idx] = ex; cur[idx] = ex; }
        __syncthreads();
        if (tid == 1023) scarry = carry + sw[15];
        __syncthreads();
    }
    if (tid == 0) rp[N] = scarry;
}

__global__ __launch_bounds__(256) void k_fill_ab(
    const int* __restrict__ src, const int* __restrict__ dst,
    int* __restrict__ cur, int* __restrict__ psrc, int* __restrict__ peid)
{
    int i = blockIdx.x * 256 + threadIdx.x;
    if (i < NB) {
        int p = atomicAdd(&cur[dst[i]], 1);
        psrc[p] = src[i];
        peid[p] = i;
    }
}

__global__ __launch_bounds__(256) void k_fill_ba(
    const int* __restrict__ src, const int* __restrict__ dst,
    const float* __restrict__ ang,
    int* __restrict__ cur, int* __restrict__ psrc, float* __restrict__ pang)
{
    int i = blockIdx.x * 256 + threadIdx.x;
    if (i < NANG) {
        int p = atomicAdd(&cur[dst[i]], 1);
        psrc[p] = src[i];
        pang[p] = ang[i];
    }
}

// ================= feature builders (A-frag tiled output) =================
__global__ __launch_bounds__(256) void k_feat_ba(
    const int* __restrict__ rp, const int* __restrict__ psrc,
    const float* __restrict__ pang, const float* __restrict__ bfloat,
    const int* __restrict__ bcat,
    ushort_t* __restrict__ aext_t, ushort_t* __restrict__ f_t)
{
    __shared__ float sf[4][16][132];
    int tid = threadIdx.x, wid = tid >> 6, lane = tid & 63;
    int g0 = blockIdx.x * 64 + wid * 16;
    for (int r = 0; r < 16; ++r) {
        int n = g0 + r;
        float v0 = 0.f, v1 = 0.f;
        if (n < NHALF) {
            int p0 = rp[n], p1 = rp[n + 1];
            for (int pb = p0; pb < p1; pb += 64) {
                int cnt = min(p1 - pb, 64);
                int cp = 0; float bv = 0.f, av = 0.f;
                if (lane < cnt) {
                    int s = psrc[pb + lane];
                    cp = (bcat[6 * s] & 15) | ((bcat[6 * s + 1] & 15) << 4) | ((bcat[6 * s + 2] & 15) << 8);
                    bv = bfloat[2 * s];
                    av = pang[pb + lane];
                }
                for (int i = 0; i < cnt; ++i) {
                    int cpi = __shfl(cp, i);
                    float bvi = __shfl(bv, i), avi = __shfl(av, i);
                    if (lane < 48) {
                        v0 += (((cpi >> ((lane >> 4) << 2)) & 15) == (lane & 15)) ? 1.f : 0.f;
                    } else {
                        float d = bvi - 0.1f * (float)(lane - 48);
                        v0 += expf(-10.f * d * d);
                    }
                    if (lane < 4) { float d = bvi - 0.1f * (float)(lane + 16); v1 += expf(-10.f * d * d); }
                    else if (lane < 36) { float d = avi - 0.1f * (float)(lane - 4); v1 += expf(-10.f * d * d); }
                    else if (lane == 36) v1 += 1.f;
                }
            }
        }
        sf[wid][r][lane] = v0;
        sf[wid][r][64 + lane] = v1;
    }
    __syncthreads();
    {
        int ar = lane & 15, aq = (lane >> 4) << 3;
        #pragma unroll
        for (int s = 0; s < 4; ++s) {
            const float* src = &sf[wid][ar][s * 32 + aq];
            uint_t pk[4];
            #pragma unroll
            for (int j = 0; j < 4; ++j)
                pk[j] = (uint_t)f2bf(src[2 * j]) | ((uint_t)f2bf(src[2 * j + 1]) << 16);
            *(uint4*)(aext_t + ((((size_t)blockIdx.x * 4 + wid) * 4 + s) * 64 + lane) * 8) =
                make_uint4(pk[0], pk[1], pk[2], pk[3]);
        }
    }
    __syncthreads();
    for (int r = 0; r < 16; ++r) {
        int n = g0 + r;
        float v0 = 0.f, v1 = 0.f;
        if (n < NHALF) {
            if (lane < 48) {
                v0 = (bcat[6 * n + (lane >> 4)] == (lane & 15)) ? 1.f : 0.f;
            } else {
                float d = bfloat[2 * n] - 0.1f * (float)(lane - 48);
                v0 = expf(-10.f * d * d);
            }
            if (lane < 4) { float d = bfloat[2 * n] - 0.1f * (float)(lane + 16); v1 = expf(-10.f * d * d); }
            else if (lane == 4) v1 = 1.f;
        }
        sf[wid][r][lane] = v0;
        sf[wid][r][64 + lane] = v1;
    }
    __syncthreads();
    {
        int ar = lane & 15, aq = (lane >> 4) << 3;
        #pragma unroll
        for (int s = 0; s < 3; ++s) {
            const float* src = &sf[wid][ar][s * 32 + aq];
            uint_t pk[4];
            #pragma unroll
            for (int j = 0; j < 4; ++j)
                pk[j] = (uint_t)f2bf(src[2 * j]) | ((uint_t)f2bf(src[2 * j + 1]) << 16);
            *(uint4*)(f_t + ((((size_t)blockIdx.x * 4 + wid) * 3 + s) * 64 + lane) * 8) =
                make_uint4(pk[0], pk[1], pk[2], pk[3]);
        }
    }
}

__global__ __launch_bounds__(256) void k_feat_ab(
    const int* __restrict__ rp, const int* __restrict__ peid,
    const float* __restrict__ bfloat, const int* __restrict__ bcat,
    ushort_t* __restrict__ fab_t)
{
    __shared__ float sf[4][16][132];
    int tid = threadIdx.x, wid = tid >> 6, lane = tid & 63;
    int g0 = blockIdx.x * 64 + wid * 16;
    for (int r = 0; r < 16; ++r) {
        int n = g0 + r;
        float v0 = 0.f, v1 = 0.f;
        if (n < NA) {
            int p0 = rp[n], p1 = rp[n + 1];
            for (int pb = p0; pb < p1; pb += 64) {
                int cnt = min(p1 - pb, 64);
                int cp = 0; float bv = 0.f;
                if (lane < cnt) {
                    int e = peid[pb + lane];
                    cp = (bcat[3 * e] & 15) | ((bcat[3 * e + 1] & 15) << 4) | ((bcat[3 * e + 2] & 15) << 8);
                    bv = bfloat[e];
                }
                for (int i = 0; i < cnt; ++i) {
                    int cpi = __shfl(cp, i);
                    float bvi = __shfl(bv, i);
                    if (lane < 48) {
                        v0 += (((cpi >> ((lane >> 4) << 2)) & 15) == (lane & 15)) ? 1.f : 0.f;
                    } else {
                        float d = bvi - 0.1f * (float)(lane - 48);
                        v0 += expf(-10.f * d * d);
                    }
                    if (lane < 4) { float d = bvi - 0.1f * (float)(lane + 16); v1 += expf(-10.f * d * d); }
                    else if (lane == 4) v1 += 1.f;
                }
            }
        }
        sf[wid][r][lane] = v0;
        sf[wid][r][64 + lane] = v1;
    }
    __syncthreads();
    int ar = lane & 15, aq = (lane >> 4) << 3;
    #pragma unroll
    for (int s = 0; s < 3; ++s) {
        const float* src = &sf[wid][ar][s * 32 + aq];
        uint_t pk[4];
        #pragma unroll
        for (int j = 0; j < 4; ++j)
            pk[j] = (uint_t)f2bf(src[2 * j]) | ((uint_t)f2bf(src[2 * j + 1]) << 16);
        *(uint4*)(fab_t + ((((size_t)blockIdx.x * 4 + wid) * 3 + s) * 64 + lane) * 8) =
            make_uint4(pk[0], pk[1], pk[2], pk[3]);
    }
}

// ================= weight folds (fp32) =================
__global__ __launch_bounds__(256) void k_fold(
    const float* __restrict__ ba_w1, const float* __restrict__ lbemb,
    const float* __restrict__ rwb, const float* __restrict__ rbvb,
    const float* __restrict__ rwa, const float* __restrict__ rbva,
    const float* __restrict__ ab_w1, const float* __restrict__ bei,
    const float* __restrict__ brw, const float* __restrict__ brb,
    float* __restrict__ W1ext, float* __restrict__ W1ab0x)
{
    int f = blockIdx.x * 256 + threadIdx.x;
    if (f < 262144) {
        int n = f & 255, k = (f >> 8) & 127, l = f >> 15;
        float v = 0.f;
        if (k <= 100) {
            const float* w1 = ba_w1 + (size_t)l * 32768 + n;
            if (k == 100) {
                const float* r1 = rbvb + (size_t)l * 128;
                const float* r2 = rbva + (size_t)l * 128;
                for (int c = 0; c < 128; ++c) v += (r1[c] + r2[c]) * w1[(size_t)c * 256];
            } else {
                const float* row = (k < 48) ? lbemb + ((size_t)l * 48 + k) * 128
                                 : (k < 68) ? rwb + ((size_t)l * 20 + (k - 48)) * 128
                                            : rwa + ((size_t)l * 32 + (k - 68)) * 128;
                for (int c = 0; c < 128; ++c) v += row[c] * w1[(size_t)c * 256];
            }
        }
        W1ext[f] = v;
    } else if (f < 286720) {
        int f2 = f - 262144;
        int n = f2 & 255, k = f2 >> 8;
        float v = 0.f;
        if (k <= 68) {
            const float* w1 = ab_w1 + n;
            const float* row = (k < 48) ? bei + (size_t)k * 128
                             : (k < 68) ? brw + (size_t)(k - 48) * 128
                                        : brb;
            for (int c = 0; c < 128; ++c) v += row[c] * w1[(size_t)c * 256];
        }
        W1ab0x[f2] = v;
    }
}

// ================= pack weights into B-frag order =================
// regions (frag units): [0,7168) W1ab0 K224; [7168,35840) ab_w1 l1-7;
// [35840,68608) W1ext_ba; [68608,134144) w2 ab+ba; [134144,146432) G
__global__ __launch_bounds__(256) void k_pack(
    const float* __restrict__ ab_w1, const float* __restrict__ W1ab0x,
    const float* __restrict__ W1ext, const float* __restrict__ ab_w2,
    const float* __restrict__ ba_w2, const float* __restrict__ lbemb,
    const float* __restrict__ rwb, const float* __restrict__ rbvb,
    ushort_t* __restrict__ wp)
{
    int f = blockIdx.x * 256 + threadIdx.x;
    if (f >= 146432) return;
    int lane = f & 63;
    int k0 = 0, n = 0, N = 256;
    const float* W = nullptr;
    float vals[8];
    if (f < 7168) {
        int ts = f >> 6; int s = ts % 7, t = ts / 7;
        k0 = s * 32 + ((lane >> 4) << 3); n = t * 16 + (lane & 15); N = 256;
        if (k0 < 128) W = ab_w1;
        else { W = W1ab0x; k0 -= 128; }
    } else if (f < 35840) {
        int f2 = f - 7168; int ts = f2 >> 6;
        int s = ts & 3, t = (ts >> 2) & 15, l = (ts >> 6) + 1;
        W = ab_w1 + (size_t)l * 32768; N = 256;
        k0 = s * 32 + ((lane >> 4) << 3); n = t * 16 + (lane & 15);
    } else if (f < 68608) {
        int f2 = f - 35840; int ts = f2 >> 6;
        int s = ts & 3, t = (ts >> 2) & 15, l = ts >> 6;
        W = W1ext + (size_t)l * 32768; N = 256;
        k0 = s * 32 + ((lane >> 4) << 3); n = t * 16 + (lane & 15);
    } else if (f < 134144) {
        int f2 = f - 68608; int ts = f2 >> 6;
        int s = ts & 7, t = (ts >> 3) & 7, l = (ts >> 6) & 7, grp = ts >> 9;
        W = (grp ? ba_w2 : ab_w2) + (size_t)l * 32768; N = 128;
        k0 = s * 32 + ((lane >> 4) << 3); n = t * 16 + (lane & 15);
    } else {
        int f2 = f - 134144; int ts = f2 >> 6;
        int s = ts % 3, t = (ts / 3) & 7, l = ts / 24;
        N = 128; k0 = s * 32 + ((lane >> 4) << 3); n = t * 16 + (lane & 15);
        #pragma unroll
        for (int j = 0; j < 8; ++j) {
            int k = k0 + j; float v;
            if (k < 48) v = lbemb[(size_t)l * 6144 + (size_t)k * 128 + n];
            else if (k < 68) v = rwb[(size_t)l * 2560 + (size_t)(k - 48) * 128 + n];
            else if (k == 68) v = rbvb[(size_t)l * 128 + n];
            else v = 0.f;
            vals[j] = v;
        }
    }
    if (W) {
        #pragma unroll
        for (int j = 0; j < 8; ++j) vals[j] = W[(size_t)(k0 + j) * N + n];
    }
    uint_t pk[4];
    #pragma unroll
    for (int j = 0; j < 4; ++j)
        pk[j] = (uint_t)f2bf(vals[2 * j]) | ((uint_t)f2bf(vals[2 * j + 1]) << 16);
    *(uint4*)(wp + (size_t)f * 8) = make_uint4(pk[0], pk[1], pk[2], pk[3]);
}

// ================= batched ba MLP — H split in two halves, 17.4KB LDS, no barrier =====
// (round-9 body, verified 97.7us) each wave uses only its own sC1 slice; c2 accumulates
// frags s=0..3 then 4..7 per accumulator (same order as monolithic) -> bitwise identical
__global__ __launch_bounds__(256) void k_ba_batch(
    const ushort_t* __restrict__ aext_t, const ushort_t* __restrict__ f_t,
    const ushort_t* __restrict__ wp,
    const float* __restrict__ ba_b1, const float* __restrict__ ba_b2,
    const float* __restrict__ ba_g, const float* __restrict__ ba_bt,
    ushort_t* __restrict__ pool, float* __restrict__ edge_out,
    int lbase, float inv_sqrt_n)
{
    __shared__ ushort_t sC1[4][16 * 136];
    int tid = threadIdx.x, wid = tid >> 6, lane = tid & 63;
    int l = lbase + (blockIdx.x & 3);
    int rb = blockIdx.x >> 2;
    const ushort_t* w1p = wp + ((size_t)35840 + (size_t)l * 4096) * 8;
    const ushort_t* w2p = wp + ((size_t)68608 + (size_t)(8 + l) * 4096) * 8;
    const ushort_t* gp  = wp + ((size_t)134144 + (size_t)l * 1536) * 8;
    const float* b1 = ba_b1 + l * HH;
    const float* b2 = ba_b2 + l * DD;
    const float* g  = ba_g + l * DD;
    const float* bt = ba_bt + l * DD;
    ushort_t* outb = pool + (size_t)(l & 3) * NHALF * DD;

    int arow = lane & 15, aq = (lane >> 4) << 3;
    int colb = lane & 15;
    int r0 = (lane >> 4) << 2;

    s16x8 af[4];
    #pragma unroll
    for (int s = 0; s < 4; ++s)
        af[s] = *(const s16x8*)(aext_t + ((((size_t)rb * 4 + wid) * 4 + s) * 64 + lane) * 8);

    f32x4 c2[8];
    #pragma unroll
    for (int t = 0; t < 8; ++t) c2[t] = (f32x4){0.f, 0.f, 0.f, 0.f};

    #pragma unroll
    for (int half = 0; half < 2; ++half) {
        for (int tt = 0; tt < 8; ++tt) {
            int t = half * 8 + tt;
            f32x4 acc = {0.f, 0.f, 0.f, 0.f};
            #pragma unroll
            for (int s = 0; s < 4; ++s) {
                s16x8 bf = *(const s16x8*)(w1p + ((size_t)(t * 4 + s) * 64 + lane) * 8);
                acc = __builtin_amdgcn_mfma_f32_16x16x32_bf16(af[s], bf, acc, 0, 0, 0);
            }
            float b1v = b1[t * 16 + colb];
            #pragma unroll
            for (int r = 0; r < 4; ++r)
                sC1[wid][(r0 + r) * 136 + tt * 16 + colb] = f2bf(fmaxf(acc[r] + b1v, 0.f));
        }
        s16x8 a2h[4];
        #pragma unroll
        for (int s = 0; s < 4; ++s)
            a2h[s] = *(const s16x8*)&sC1[wid][arow * 136 + s * 32 + aq];
        for (int t = 0; t < 8; ++t) {
            #pragma unroll
            for (int s = 0; s < 4; ++s) {
                s16x8 bf = *(const s16x8*)(w2p + ((size_t)(t * 8 + half * 4 + s) * 64 + lane) * 8);
                c2[t] = __builtin_amdgcn_mfma_f32_16x16x32_bf16(a2h[s], bf, c2[t], 0, 0, 0);
            }
        }
    }

    s16x8 af3[3];
    #pragma unroll
    for (int s = 0; s < 3; ++s)
        af3[s] = *(const s16x8*)(f_t + ((((size_t)rb * 4 + wid) * 3 + s) * 64 + lane) * 8);

    {
        float b2v[8];
        #pragma unroll
        for (int t = 0; t < 8; ++t) b2v[t] = b2[t * 16 + colb];
        #pragma unroll
        for (int t = 0; t < 8; ++t)
            #pragma unroll
            for (int r = 0; r < 4; ++r) c2[t][r] += b2v[t];
    }
    float mu4[4], rs4[4];
    #pragma unroll
    for (int r = 0; r < 4; ++r) {
        float s = 0.f, ss = 0.f;
        #pragma unroll
        for (int t = 0; t < 8; ++t) { float x = c2[t][r]; s += x; ss += x * x; }
        #pragma unroll
        for (int m = 1; m < 16; m <<= 1) {
            s  += __shfl_xor(s, m);
            ss += __shfl_xor(ss, m);
        }
        float mu = s * (1.f / 128.f);
        float var = ss * (1.f / 128.f) - mu * mu;
        mu4[r] = mu;
        rs4[r] = rsqrtf(var + 1e-5f);
    }
    int growb = rb * 64 + wid * 16 + r0;
    #pragma unroll
    for (int t = 0; t < 8; ++t) {
        f32x4 racc = {0.f, 0.f, 0.f, 0.f};
        #pragma unroll
        for (int s = 0; s < 3; ++s) {
            s16x8 bf = *(const s16x8*)(gp + ((size_t)(t * 3 + s) * 64 + lane) * 8);
            racc = __builtin_amdgcn_mfma_f32_16x16x32_bf16(af3[s], bf, racc, 0, 0, 0);
        }
        int n = t * 16 + colb;
        float gv = g[n], btv = bt[n];
        #pragma unroll
        for (int r = 0; r < 4; ++r) {
            int grow = growb + r;
            if (grow < NHALF) {
                float y = (c2[t][r] - mu4[r]) * rs4[r] * gv + btv;
                float o = fmaxf(y * inv_sqrt_n, 0.f) + racc[r];
                if (l < 7) {
                    outb[(size_t)grow * DD + n] = f2bf(o);
                } else {
                    edge_out[(size_t)(2 * grow) * DD + n] = o;
                    edge_out[(size_t)(2 * grow + 1) * DD + n] = o;
                }
            }
        }
    }
}

// ================= standalone gather: one wave per dst row =================
template<bool L0>
__global__ __launch_bounds__(256) void k_gather(
    const uint_t* __restrict__ node2, const uint_t* __restrict__ half2,
    const int* __restrict__ rp, const int* __restrict__ psrc,
    const int* __restrict__ peid, uint_t* __restrict__ agg)
{
    int wid = threadIdx.x >> 6, lane = threadIdx.x & 63;
    int n = blockIdx.x * 4 + wid;
    if (n >= 30016) return;
    float v0 = 0.f, v1 = 0.f;
    if (n < NA) {
        int p0 = rp[n], p1 = rp[n + 1];
        for (int pb = p0; pb < p1; pb += 64) {
            int cnt = min(p1 - pb, 64);
            int sv = 0, ev = 0;
            if (lane < cnt) {
                sv = psrc[pb + lane];
                if (!L0) ev = peid[pb + lane] >> 1;
            }
            for (int i = 0; i < cnt; i += 4) {
                bool c1 = (i + 1 < cnt), c2m = (i + 2 < cnt), c3 = (i + 3 < cnt);
                int s0 = __shfl(sv, i);
                int s1 = __shfl(sv, c1 ? i + 1 : i);
                int s2 = __shfl(sv, c2m ? i + 2 : i);
                int s3 = __shfl(sv, c3 ? i + 3 : i);
                uint_t a0 = node2[(size_t)s0 * 64 + lane];
                uint_t a1 = node2[(size_t)s1 * 64 + lane];
                uint_t a2 = node2[(size_t)s2 * 64 + lane];
                uint_t a3 = node2[(size_t)s3 * 64 + lane];
                uint_t h0 = 0, h1 = 0, h2 = 0, h3 = 0;
                if (!L0) {
                    int e0 = __shfl(ev, i);
                    int e1 = __shfl(ev, c1 ? i + 1 : i);
                    int e2 = __shfl(ev, c2m ? i + 2 : i);
                    int e3 = __shfl(ev, c3 ? i + 3 : i);
                    h0 = half2[(size_t)e0 * 64 + lane];
                    h1 = half2[(size_t)e1 * 64 + lane];
                    h2 = half2[(size_t)e2 * 64 + lane];
                    h3 = half2[(size_t)e3 * 64 + lane];
                }
                v0 += bf2f((ushort_t)(a0 & 0xffff));
                v1 += bf2f((ushort_t)(a0 >> 16));
                if (!L0) { v0 += bf2f((ushort_t)(h0 & 0xffff)); v1 += bf2f((ushort_t)(h0 >> 16)); }
                if (c1) {
                    v0 += bf2f((ushort_t)(a1 & 0xffff));
                    v1 += bf2f((ushort_t)(a1 >> 16));
                    if (!L0) { v0 += bf2f((ushort_t)(h1 & 0xffff)); v1 += bf2f((ushort_t)(h1 >> 16)); }
                }
                if (c2m) {
                    v0 += bf2f((ushort_t)(a2 & 0xffff));
                    v1 += bf2f((ushort_t)(a2 >> 16));
                    if (!L0) { v0 += bf2f((ushort_t)(h2 & 0xffff)); v1 += bf2f((ushort_t)(h2 >> 16)); }
                }
                if (c3) {
                    v0 += bf2f((ushort_t)(a3 & 0xffff));
                    v1 += bf2f((ushort_t)(a3 >> 16));
                    if (!L0) { v0 += bf2f((ushort_t)(h3 & 0xffff)); v1 += bf2f((ushort_t)(h3 >> 16)); }
                }
            }
        }
    }
    agg[(size_t)n * 64 + lane] = (uint_t)f2bf(v0) | ((uint_t)f2bf(v1) << 16);
}

// ================= MLP only (ab path) — round-3 monolithic body (verified ~25us) ======
template<int KS, bool L0>
__global__ __launch_bounds__(256) void k_mlp_ab(
    const ushort_t* __restrict__ agg, const ushort_t* __restrict__ fab_t,
    const ushort_t* __restrict__ w1p, const float* __restrict__ b1,
    const ushort_t* __restrict__ w2p, const float* __restrict__ b2,
    const float* __restrict__ g, const float* __restrict__ bt,
    const float* __restrict__ resid, float* __restrict__ outf,
    ushort_t* __restrict__ outb, float inv_sqrt_n)
{
    __shared__ ushort_t sC1[4][16 * 264];
    int tid = threadIdx.x, wid = tid >> 6, lane = tid & 63;
    int g0 = blockIdx.x * 64 + wid * 16;

    int arow = lane & 15, aq = (lane >> 4) << 3;
    s16x8 af[KS];
    #pragma unroll
    for (int s = 0; s < 4; ++s)
        af[s] = *(const s16x8*)(agg + (size_t)(g0 + arow) * 128 + s * 32 + aq);
    if (L0) {
        #pragma unroll
        for (int s = 0; s < 3; ++s)
            af[4 + s] = *(const s16x8*)(fab_t + ((((size_t)blockIdx.x * 4 + wid) * 3 + s) * 64 + lane) * 8);
    }

    for (int t = 0; t < 16; ++t) {
        f32x4 acc = {0.f, 0.f, 0.f, 0.f};
        #pragma unroll
        for (int s = 0; s < KS; ++s) {
            s16x8 bf = *(const s16x8*)(w1p + ((size_t)(t * KS + s) * 64 + lane) * 8);
            acc = __builtin_amdgcn_mfma_f32_16x16x32_bf16(af[s], bf, acc, 0, 0, 0);
        }
        int n = t * 16 + (lane & 15);
        float b1v = b1[n];
        int r0 = (lane >> 4) << 2;
        #pragma unroll
        for (int r = 0; r < 4; ++r)
            sC1[wid][(r0 + r) * 264 + n] = f2bf(fmaxf(acc[r] + b1v, 0.f));
    }
    __syncthreads();

    s16x8 a2[8];
    #pragma unroll
    for (int s = 0; s < 8; ++s) a2[s] = *(const s16x8*)&sC1[wid][arow * 264 + s * 32 + aq];
    f32x4 c2[8];
    for (int t = 0; t < 8; ++t) {
        f32x4 acc = {0.f, 0.f, 0.f, 0.f};
        #pragma unroll
        for (int s = 0; s < 8; ++s) {
            s16x8 bf = *(const s16x8*)(w2p + ((size_t)(t * 8 + s) * 64 + lane) * 8);
            acc = __builtin_amdgcn_mfma_f32_16x16x32_bf16(a2[s], bf, acc, 0, 0, 0);
        }
        c2[t] = acc;
    }

    int colb = lane & 15;
    float b2v[8], gv[8], btv[8];
    #pragma unroll
    for (int t = 0; t < 8; ++t) {
        int n = t * 16 + colb;
        b2v[t] = b2[n]; gv[t] = g[n]; btv[t] = bt[n];
    }
    #pragma unroll
    for (int t = 0; t < 8; ++t)
        #pragma unroll
        for (int r = 0; r < 4; ++r) c2[t][r] += b2v[t];

    int r0 = (lane >> 4) << 2;
    #pragma unroll
    for (int r = 0; r < 4; ++r) {
        float s = 0.f, ss = 0.f;
        #pragma unroll
        for (int t = 0; t < 8; ++t) { float x = c2[t][r]; s += x; ss += x * x; }
        #pragma unroll
        for (int m = 1; m < 16; m <<= 1) {
            s  += __shfl_xor(s, m);
            ss += __shfl_xor(ss, m);
        }
        float mu = s * (1.f / 128.f);
        float var = ss * (1.f / 128.f) - mu * mu;
        float rstd = rsqrtf(var + 1e-5f);
        int grow = g0 + r0 + r;
        if (grow < NA) {
            #pragma unroll
            for (int t = 0; t < 8; ++t) {
                int n = t * 16 + colb;
                float y = (c2[t][r] - mu) * rstd * gv[t] + btv[t];
                float o = fmaxf(y * inv_sqrt_n, 0.f) + resid[(size_t)grow * DD + n];
                outf[(size_t)grow * DD + n] = o;
                outb[(size_t)grow * DD + n] = f2bf(o);
            }
        }
    }
}

// ---------------- graph = node.mean(axis=0)
__global__ __launch_bounds__(256) void k_graph_mean(
    const float* __restrict__ node, float* __restrict__ graph)
{
    int tid = threadIdx.x;
    int c = tid & 127, h = tid >> 7;
    const int rpb = 250;
    int r0 = blockIdx.x * rpb;
    float s = 0.f;
    for (int r = r0 + h; r < r0 + rpb; r += 2) s += node[(size_t)r * DD + c];
    __shared__ float sS[256];
    sS[tid] = s;
    __syncthreads();
    if (tid < 128) atomicAdd(&graph[c], (sS[tid] + sS[tid + 128]) * (1.f / 30000.f));
}

extern "C" void kernel_launch(void* const* d_in, const int* in_sizes, int n_in,
                              void* d_out, int out_size, void* d_ws, size_t ws_size,
                              hipStream_t stream)
{
    const int*   atom_cat         = (const int*)d_in[0];
    const int*   bond_cat         = (const int*)d_in[1];
    const float* bond_float       = (const float*)d_in[2];
    const float* angle_float      = (const float*)d_in[3];
    const int*   ab_src           = (const int*)d_in[4];
    const int*   ab_dst           = (const int*)d_in[5];
    const int*   ba_src           = (const int*)d_in[6];
    const int*   ba_dst           = (const int*)d_in[7];
    const float* atom_emb         = (const float*)d_in[8];
    const float* bond_emb_init    = (const float*)d_in[9];
    const float* bond_rbf_w_init  = (const float*)d_in[10];
    const float* bond_rbf_b_init  = (const float*)d_in[11];
    const float* layer_bond_emb   = (const float*)d_in[12];
    const float* layer_bond_rbf_w = (const float*)d_in[13];
    const float* layer_bond_rbf_b = (const float*)d_in[14];
    const float* layer_angle_rbf_w= (const float*)d_in[15];
    const float* layer_angle_rbf_b= (const float*)d_in[16];
    const float* ab_w1 = (const float*)d_in[17];
    const float* ab_b1 = (const float*)d_in[18];
    const float* ab_w2 = (const float*)d_in[19];
    const float* ab_b2 = (const float*)d_in[20];
    const float* ab_g  = (const float*)d_in[21];
    const float* ab_bt = (const float*)d_in[22];
    const float* ba_w1 = (const float*)d_in[23];
    const float* ba_b1 = (const float*)d_in[24];
    const float* ba_w2 = (const float*)d_in[25];
    const float* ba_b2 = (const float*)d_in[26];
    const float* ba_g  = (const float*)d_in[27];
    const float* ba_bt = (const float*)d_in[28];

    float* node     = (float*)d_out;
    float* edge_out = node + (size_t)NA * DD;
    float* graph    = edge_out + (size_t)NB * DD;

    // ---- ws layout
    ushort_t* nbf0   = (ushort_t*)d_ws;                        // NA*128
    ushort_t* nbf1   = nbf0 + (size_t)NA * DD;                 // NA*128
    ushort_t* pool   = nbf1 + (size_t)NA * DD;                 // 4*NHALF*128
    ushort_t* aext_t = pool + (size_t)4 * NHALF * DD;          // 782*8192
    ushort_t* f_t    = aext_t + (size_t)782 * 8192;            // 782*6144
    ushort_t* fab_t  = f_t + (size_t)782 * 6144;               // 469*6144
    ushort_t* wp     = fab_t + (size_t)469 * 6144;             // 146432*8
    float*    W1ext  = (float*)(wp + (size_t)146432 * 8);      // 262144
    float*    W1ab0x = W1ext + 262144;                         // 24576
    int*      cur_ab = (int*)(W1ab0x + 24576);                 // NA
    int*      cur_ba = cur_ab + NA;                            // NHALF
    int*      rp_ab  = cur_ba + NHALF;                         // NA+1
    int*      rp_ba  = rp_ab + NA + 1;                         // NHALF+1
    int*      psrc_ab= rp_ba + NHALF + 1;                      // NB
    int*      peid_ab= psrc_ab + NB;                           // NB
    int*      psrc_ba= peid_ab + NB;                           // NANG
    float*    pang   = (float*)(psrc_ba + NANG);               // NANG
    uint_t*   agg    = (uint_t*)(pang + NANG);                 // 30016*64

    const float isn_a = (float)(1.0 / sqrt(30000.0));
    const float isn_h = (float)(1.0 / sqrt(50000.0));

    // ---- CSR build
    hipMemsetAsync(cur_ab, 0, (size_t)(NA + NHALF) * sizeof(int), stream);
    k_hist2<<<(NB + NANG + 255) / 256, 256, 0, stream>>>(ab_dst, cur_ab, ba_dst, cur_ba);
    k_scan<<<2, 1024, 0, stream>>>(cur_ab, rp_ab, cur_ba, rp_ba);
    k_fill_ab<<<(NB + 255) / 256, 256, 0, stream>>>(ab_src, ab_dst, cur_ab, psrc_ab, peid_ab);
    k_fill_ba<<<(NANG + 255) / 256, 256, 0, stream>>>(ba_src, ba_dst, angle_float, cur_ba, psrc_ba, pang);

    // ---- features + folds + packing
    k_feat_ba<<<782, 256, 0, stream>>>(rp_ba, psrc_ba, pang, bond_float, bond_cat, aext_t, f_t);
    k_feat_ab<<<469, 256, 0, stream>>>(rp_ab, peid_ab, bond_float, bond_cat, fab_t);
    k_fold<<<1120, 256, 0, stream>>>(ba_w1, layer_bond_emb, layer_bond_rbf_w,
        layer_bond_rbf_b, layer_angle_rbf_w, layer_angle_rbf_b,
        ab_w1, bond_emb_init, bond_rbf_w_init, bond_rbf_b_init, W1ext, W1ab0x);
    k_pack<<<572, 256, 0, stream>>>(ab_w1, W1ab0x, W1ext, ab_w2, ba_w2,
        layer_bond_emb, layer_bond_rbf_w, layer_bond_rbf_b, wp);

    k_node_init<<<NA / 2, 256, 0, stream>>>(atom_cat, atom_emb, node, nbf0);

    // ---- batched ba layers 0-3 -> pool[0..3]
    k_ba_batch<<<782 * 4, 256, 0, stream>>>(aext_t, f_t, wp, ba_b1, ba_b2, ba_g, ba_bt,
        pool, edge_out, 0, isn_h);

    ushort_t* nbf[2] = {nbf0, nbf1};
    for (int l = 0; l < LL; ++l) {
        const uint_t* rd = (const uint_t*)nbf[l & 1];
        ushort_t* wr = nbf[1 - (l & 1)];
        const uint_t* halfbuf = (const uint_t*)(pool + (size_t)((l - 1) & 3) * NHALF * DD);
        const ushort_t* ab_w1p = l ? wp + ((size_t)7168 + (size_t)(l - 1) * 4096) * 8 : wp;
        const ushort_t* ab_w2p = wp + ((size_t)68608 + (size_t)l * 4096) * 8;

        if (l == 0) {
            k_gather<true><<<7504, 256, 0, stream>>>(rd, rd, rp_ab, psrc_ab, peid_ab, agg);
            k_mlp_ab<7, true><<<469, 256, 0, stream>>>(
                (const ushort_t*)agg, fab_t,
                ab_w1p, ab_b1, ab_w2p, ab_b2, ab_g, ab_bt,
                node, node, wr, isn_a);
        } else {
            k_gather<false><<<7504, 256, 0, stream>>>(rd, halfbuf, rp_ab, psrc_ab, peid_ab, agg);
            k_mlp_ab<4, false><<<469, 256, 0, stream>>>(
                (const ushort_t*)agg, fab_t,
                ab_w1p, ab_b1 + l * HH, ab_w2p, ab_b2 + l * DD,
                ab_g + l * DD, ab_bt + l * DD, node, node, wr, isn_a);
        }

        if (l == 3)   // pool[0..2] consumed; refill with layers 4-6 (+edge from 7)
            k_ba_batch<<<782 * 4, 256, 0, stream>>>(aext_t, f_t, wp, ba_b1, ba_b2, ba_g, ba_bt,
                pool, edge_out, 4, isn_h);
    }

    hipMemsetAsync(graph, 0, DD * sizeof(float), stream);
    k_graph_mean<<<120, 256, 0, stream>>>(node, graph);
}

// Round 12
// 796.509 us; speedup vs baseline: 1.2068x; 1.0001x over previous
//
#include <hip/hip_runtime.h>
#include <math.h>

#define NA 30000
#define NB 100000
#define NHALF 50000
#define NANG 200000
#define DD 128
#define HH 256
#define LL 8

typedef unsigned short ushort_t;
typedef unsigned int uint_t;
typedef short s16x8 __attribute__((ext_vector_type(8)));
typedef float f32x4 __attribute__((ext_vector_type(4)));

__device__ __forceinline__ ushort_t f2bf(float x) {
    unsigned int u = __builtin_bit_cast(unsigned int, x);
    u += 0x7fff + ((u >> 16) & 1);
    return (ushort_t)(u >> 16);
}
__device__ __forceinline__ float bf2f(ushort_t b) {
    unsigned int u = ((unsigned int)b) << 16;
    return __builtin_bit_cast(float, u);
}

// ---------------- node init (fp32 + bf16 shadow)
__global__ __launch_bounds__(256) void k_node_init(
    const int* __restrict__ cat, const float* __restrict__ emb,
    float* __restrict__ node, ushort_t* __restrict__ node_bf)
{
    int tid = threadIdx.x;
    int r = blockIdx.x * 2 + (tid >> 7);
    int c = tid & 127;
    const int* cr = cat + r * 9;
    float v = 0.f;
    #pragma unroll
    for (int i = 0; i < 9; ++i) v += emb[((i << 6) + cr[i]) * DD + c];
    node[(size_t)r * DD + c] = v;
    node_bf[(size_t)r * DD + c] = f2bf(v);
}

// ================= CSR build =================
__global__ __launch_bounds__(256) void k_hist2(
    const int* __restrict__ ab_dst, int* __restrict__ cur_ab,
    const int* __restrict__ ba_dst, int* __restrict__ cur_ba)
{
    int i = blockIdx.x * 256 + threadIdx.x;
    if (i < NB) atomicAdd(&cur_ab[ab_dst[i]], 1);
    int j = i - NB;
    if (j >= 0 && j < NANG) atomicAdd(&cur_ba[ba_dst[j]], 1);
}

__global__ __launch_bounds__(1024) void k_scan(
    int* __restrict__ cur_ab, int* __restrict__ rp_ab,
    int* __restrict__ cur_ba, int* __restrict__ rp_ba)
{
    int N; int* cur; int* rp;
    if (blockIdx.x == 0) { cur = cur_ab; rp = rp_ab; N = NA; }
    else                 { cur = cur_ba; rp = rp_ba; N = NHALF; }
    __shared__ int sw[16];
    __shared__ int scarry;
    int tid = threadIdx.x;
    int wid = tid >> 6, lane = tid & 63;
    if (tid == 0) scarry = 0;
    __syncthreads();
    for (int base = 0; base < N; base += 1024) {
        int idx = base + tid;
        int x = (idx < N) ? cur[idx] : 0;
        int v = x;
        #pragma unroll
        for (int off = 1; off < 64; off <<= 1) {
            int t = __shfl_up(v, off);
            if (lane >= off) v += t;
        }
        if (lane == 63) sw[wid] = v;
        __syncthreads();
        if (wid == 0) {
            int wv = (lane < 16) ? sw[lane] : 0;
            #pragma unroll
            for (int off = 1; off < 16; off <<= 1) {
                int t = __shfl_up(wv, off);
                if (lane >= off) wv += t;
            }
            if (lane < 16) sw[lane] = wv;
        }
        __syncthreads();
        int wpre = (wid > 0) ? sw[wid - 1] : 0;
        int carry = scarry;
        int ex = carry + wpre + v - x;
        if (idx < N) { rp[idx] = ex; cur[idx] = ex; }
        __syncthreads();
        if (tid == 1023) scarry = carry + sw[15];
        __syncthreads();
    }
    if (tid == 0) rp[N] = scarry;
}

__global__ __launch_bounds__(256) void k_fill_ab(
    const int* __restrict__ src, const int* __restrict__ dst,
    int* __restrict__ cur, int* __restrict__ psrc, int* __restrict__ peid)
{
    int i = blockIdx.x * 256 + threadIdx.x;
    if (i < NB) {
        int p = atomicAdd(&cur[dst[i]], 1);
        psrc[p] = src[i];
        peid[p] = i;
    }
}

__global__ __launch_bounds__(256) void k_fill_ba(
    const int* __restrict__ src, const int* __restrict__ dst,
    const float* __restrict__ ang,
    int* __restrict__ cur, int* __restrict__ psrc, float* __restrict__ pang)
{
    int i = blockIdx.x * 256 + threadIdx.x;
    if (i < NANG) {
        int p = atomicAdd(&cur[dst[i]], 1);
        psrc[p] = src[i];
        pang[p] = ang[i];
    }
}

// ================= feature builders (A-frag tiled output) =================
// sf slices are wave-private (always indexed [wid]) -> no barriers needed;
// in-wave ds_write->ds_read ordering via compiler lgkmcnt (round-9-validated)
__global__ __launch_bounds__(256) void k_feat_ba(
    const int* __restrict__ rp, const int* __restrict__ psrc,
    const float* __restrict__ pang, const float* __restrict__ bfloat,
    const int* __restrict__ bcat,
    ushort_t* __restrict__ aext_t, ushort_t* __restrict__ f_t)
{
    __shared__ float sf[4][16][132];
    int tid = threadIdx.x, wid = tid >> 6, lane = tid & 63;
    int g0 = blockIdx.x * 64 + wid * 16;
    for (int r = 0; r < 16; ++r) {
        int n = g0 + r;
        float v0 = 0.f, v1 = 0.f;
        if (n < NHALF) {
            int p0 = rp[n], p1 = rp[n + 1];
            for (int pb = p0; pb < p1; pb += 64) {
                int cnt = min(p1 - pb, 64);
                int cp = 0; float bv = 0.f, av = 0.f;
                if (lane < cnt) {
                    int s = psrc[pb + lane];
                    cp = (bcat[6 * s] & 15) | ((bcat[6 * s + 1] & 15) << 4) | ((bcat[6 * s + 2] & 15) << 8);
                    bv = bfloat[2 * s];
                    av = pang[pb + lane];
                }
                for (int i = 0; i < cnt; ++i) {
                    int cpi = __shfl(cp, i);
                    float bvi = __shfl(bv, i), avi = __shfl(av, i);
                    if (lane < 48) {
                        v0 += (((cpi >> ((lane >> 4) << 2)) & 15) == (lane & 15)) ? 1.f : 0.f;
                    } else {
                        float d = bvi - 0.1f * (float)(lane - 48);
                        v0 += expf(-10.f * d * d);
                    }
                    if (lane < 4) { float d = bvi - 0.1f * (float)(lane + 16); v1 += expf(-10.f * d * d); }
                    else if (lane < 36) { float d = avi - 0.1f * (float)(lane - 4); v1 += expf(-10.f * d * d); }
                    else if (lane == 36) v1 += 1.f;
                }
            }
        }
        sf[wid][r][lane] = v0;
        sf[wid][r][64 + lane] = v1;
    }
    {
        int ar = lane & 15, aq = (lane >> 4) << 3;
        #pragma unroll
        for (int s = 0; s < 4; ++s) {
            const float* src = &sf[wid][ar][s * 32 + aq];
            uint_t pk[4];
            #pragma unroll
            for (int j = 0; j < 4; ++j)
                pk[j] = (uint_t)f2bf(src[2 * j]) | ((uint_t)f2bf(src[2 * j + 1]) << 16);
            *(uint4*)(aext_t + ((((size_t)blockIdx.x * 4 + wid) * 4 + s) * 64 + lane) * 8) =
                make_uint4(pk[0], pk[1], pk[2], pk[3]);
        }
    }
    for (int r = 0; r < 16; ++r) {
        int n = g0 + r;
        float v0 = 0.f, v1 = 0.f;
        if (n < NHALF) {
            if (lane < 48) {
                v0 = (bcat[6 * n + (lane >> 4)] == (lane & 15)) ? 1.f : 0.f;
            } else {
                float d = bfloat[2 * n] - 0.1f * (float)(lane - 48);
                v0 = expf(-10.f * d * d);
            }
            if (lane < 4) { float d = bfloat[2 * n] - 0.1f * (float)(lane + 16); v1 = expf(-10.f * d * d); }
            else if (lane == 4) v1 = 1.f;
        }
        sf[wid][r][lane] = v0;
        sf[wid][r][64 + lane] = v1;
    }
    {
        int ar = lane & 15, aq = (lane >> 4) << 3;
        #pragma unroll
        for (int s = 0; s < 3; ++s) {
            const float* src = &sf[wid][ar][s * 32 + aq];
            uint_t pk[4];
            #pragma unroll
            for (int j = 0; j < 4; ++j)
                pk[j] = (uint_t)f2bf(src[2 * j]) | ((uint_t)f2bf(src[2 * j + 1]) << 16);
            *(uint4*)(f_t + ((((size_t)blockIdx.x * 4 + wid) * 3 + s) * 64 + lane) * 8) =
                make_uint4(pk[0], pk[1], pk[2], pk[3]);
        }
    }
}

__global__ __launch_bounds__(256) void k_feat_ab(
    const int* __restrict__ rp, const int* __restrict__ peid,
    const float* __restrict__ bfloat, const int* __restrict__ bcat,
    ushort_t* __restrict__ fab_t)
{
    __shared__ float sf[4][16][132];
    int tid = threadIdx.x, wid = tid >> 6, lane = tid & 63;
    int g0 = blockIdx.x * 64 + wid * 16;
    for (int r = 0; r < 16; ++r) {
        int n = g0 + r;
        float v0 = 0.f, v1 = 0.f;
        if (n < NA) {
            int p0 = rp[n], p1 = rp[n + 1];
            for (int pb = p0; pb < p1; pb += 64) {
                int cnt = min(p1 - pb, 64);
                int cp = 0; float bv = 0.f;
                if (lane < cnt) {
                    int e = peid[pb + lane];
                    cp = (bcat[3 * e] & 15) | ((bcat[3 * e + 1] & 15) << 4) | ((bcat[3 * e + 2] & 15) << 8);
                    bv = bfloat[e];
                }
                for (int i = 0; i < cnt; ++i) {
                    int cpi = __shfl(cp, i);
                    float bvi = __shfl(bv, i);
                    if (lane < 48) {
                        v0 += (((cpi >> ((lane >> 4) << 2)) & 15) == (lane & 15)) ? 1.f : 0.f;
                    } else {
                        float d = bvi - 0.1f * (float)(lane - 48);
                        v0 += expf(-10.f * d * d);
                    }
                    if (lane < 4) { float d = bvi - 0.1f * (float)(lane + 16); v1 += expf(-10.f * d * d); }
                    else if (lane == 4) v1 += 1.f;
                }
            }
        }
        sf[wid][r][lane] = v0;
        sf[wid][r][64 + lane] = v1;
    }
    int ar = lane & 15, aq = (lane >> 4) << 3;
    #pragma unroll
    for (int s = 0; s < 3; ++s) {
        const float* src = &sf[wid][ar][s * 32 + aq];
        uint_t pk[4];
        #pragma unroll
        for (int j = 0; j < 4; ++j)
            pk[j] = (uint_t)f2bf(src[2 * j]) | ((uint_t)f2bf(src[2 * j + 1]) << 16);
        *(uint4*)(fab_t + ((((size_t)blockIdx.x * 4 + wid) * 3 + s) * 64 + lane) * 8) =
            make_uint4(pk[0], pk[1], pk[2], pk[3]);
    }
}

// ================= weight folds (fp32) =================
__global__ __launch_bounds__(256) void k_fold(
    const float* __restrict__ ba_w1, const float* __restrict__ lbemb,
    const float* __restrict__ rwb, const float* __restrict__ rbvb,
    const float* __restrict__ rwa, const float* __restrict__ rbva,
    const float* __restrict__ ab_w1, const float* __restrict__ bei,
    const float* __restrict__ brw, const float* __restrict__ brb,
    float* __restrict__ W1ext, float* __restrict__ W1ab0x)
{
    int f = blockIdx.x * 256 + threadIdx.x;
    if (f < 262144) {
        int n = f & 255, k = (f >> 8) & 127, l = f >> 15;
        float v = 0.f;
        if (k <= 100) {
            const float* w1 = ba_w1 + (size_t)l * 32768 + n;
            if (k == 100) {
                const float* r1 = rbvb + (size_t)l * 128;
                const float* r2 = rbva + (size_t)l * 128;
                for (int c = 0; c < 128; ++c) v += (r1[c] + r2[c]) * w1[(size_t)c * 256];
            } else {
                const float* row = (k < 48) ? lbemb + ((size_t)l * 48 + k) * 128
                                 : (k < 68) ? rwb + ((size_t)l * 20 + (k - 48)) * 128
                                            : rwa + ((size_t)l * 32 + (k - 68)) * 128;
                for (int c = 0; c < 128; ++c) v += row[c] * w1[(size_t)c * 256];
            }
        }
        W1ext[f] = v;
    } else if (f < 286720) {
        int f2 = f - 262144;
        int n = f2 & 255, k = f2 >> 8;
        float v = 0.f;
        if (k <= 68) {
            const float* w1 = ab_w1 + n;
            const float* row = (k < 48) ? bei + (size_t)k * 128
                             : (k < 68) ? brw + (size_t)(k - 48) * 128
                                        : brb;
            for (int c = 0; c < 128; ++c) v += row[c] * w1[(size_t)c * 256];
        }
        W1ab0x[f2] = v;
    }
}

// ================= pack weights into B-frag order =================
// regions (frag units): [0,7168) W1ab0 K224; [7168,35840) ab_w1 l1-7;
// [35840,68608) W1ext_ba; [68608,134144) w2 ab+ba; [134144,146432) G
__global__ __launch_bounds__(256) void k_pack(
    const float* __restrict__ ab_w1, const float* __restrict__ W1ab0x,
    const float* __restrict__ W1ext, const float* __restrict__ ab_w2,
    const float* __restrict__ ba_w2, const float* __restrict__ lbemb,
    const float* __restrict__ rwb, const float* __restrict__ rbvb,
    ushort_t* __restrict__ wp)
{
    int f = blockIdx.x * 256 + threadIdx.x;
    if (f >= 146432) return;
    int lane = f & 63;
    int k0 = 0, n = 0, N = 256;
    const float* W = nullptr;
    float vals[8];
    if (f < 7168) {
        int ts = f >> 6; int s = ts % 7, t = ts / 7;
        k0 = s * 32 + ((lane >> 4) << 3); n = t * 16 + (lane & 15); N = 256;
        if (k0 < 128) W = ab_w1;
        else { W = W1ab0x; k0 -= 128; }
    } else if (f < 35840) {
        int f2 = f - 7168; int ts = f2 >> 6;
        int s = ts & 3, t = (ts >> 2) & 15, l = (ts >> 6) + 1;
        W = ab_w1 + (size_t)l * 32768; N = 256;
        k0 = s * 32 + ((lane >> 4) << 3); n = t * 16 + (lane & 15);
    } else if (f < 68608) {
        int f2 = f - 35840; int ts = f2 >> 6;
        int s = ts & 3, t = (ts >> 2) & 15, l = ts >> 6;
        W = W1ext + (size_t)l * 32768; N = 256;
        k0 = s * 32 + ((lane >> 4) << 3); n = t * 16 + (lane & 15);
    } else if (f < 134144) {
        int f2 = f - 68608; int ts = f2 >> 6;
        int s = ts & 7, t = (ts >> 3) & 7, l = (ts >> 6) & 7, grp = ts >> 9;
        W = (grp ? ba_w2 : ab_w2) + (size_t)l * 32768; N = 128;
        k0 = s * 32 + ((lane >> 4) << 3); n = t * 16 + (lane & 15);
    } else {
        int f2 = f - 134144; int ts = f2 >> 6;
        int s = ts % 3, t = (ts / 3) & 7, l = ts / 24;
        N = 128; k0 = s * 32 + ((lane >> 4) << 3); n = t * 16 + (lane & 15);
        #pragma unroll
        for (int j = 0; j < 8; ++j) {
            int k = k0 + j; float v;
            if (k < 48) v = lbemb[(size_t)l * 6144 + (size_t)k * 128 + n];
            else if (k < 68) v = rwb[(size_t)l * 2560 + (size_t)(k - 48) * 128 + n];
            else if (k == 68) v = rbvb[(size_t)l * 128 + n];
            else v = 0.f;
            vals[j] = v;
        }
    }
    if (W) {
        #pragma unroll
        for (int j = 0; j < 8; ++j) vals[j] = W[(size_t)(k0 + j) * N + n];
    }
    uint_t pk[4];
    #pragma unroll
    for (int j = 0; j < 4; ++j)
        pk[j] = (uint_t)f2bf(vals[2 * j]) | ((uint_t)f2bf(vals[2 * j + 1]) << 16);
    *(uint4*)(wp + (size_t)f * 8) = make_uint4(pk[0], pk[1], pk[2], pk[3]);
}

// ================= batched ba MLP — H split in two halves, 17.4KB LDS, no barrier =====
// (round-9 body, verified 97.7us)
__global__ __launch_bounds__(256) void k_ba_batch(
    const ushort_t* __restrict__ aext_t, const ushort_t* __restrict__ f_t,
    const ushort_t* __restrict__ wp,
    const float* __restrict__ ba_b1, const float* __restrict__ ba_b2,
    const float* __restrict__ ba_g, const float* __restrict__ ba_bt,
    ushort_t* __restrict__ pool, float* __restrict__ edge_out,
    int lbase, float inv_sqrt_n)
{
    __shared__ ushort_t sC1[4][16 * 136];
    int tid = threadIdx.x, wid = tid >> 6, lane = tid & 63;
    int l = lbase + (blockIdx.x & 3);
    int rb = blockIdx.x >> 2;
    const ushort_t* w1p = wp + ((size_t)35840 + (size_t)l * 4096) * 8;
    const ushort_t* w2p = wp + ((size_t)68608 + (size_t)(8 + l) * 4096) * 8;
    const ushort_t* gp  = wp + ((size_t)134144 + (size_t)l * 1536) * 8;
    const float* b1 = ba_b1 + l * HH;
    const float* b2 = ba_b2 + l * DD;
    const float* g  = ba_g + l * DD;
    const float* bt = ba_bt + l * DD;
    ushort_t* outb = pool + (size_t)(l & 3) * NHALF * DD;

    int arow = lane & 15, aq = (lane >> 4) << 3;
    int colb = lane & 15;
    int r0 = (lane >> 4) << 2;

    s16x8 af[4];
    #pragma unroll
    for (int s = 0; s < 4; ++s)
        af[s] = *(const s16x8*)(aext_t + ((((size_t)rb * 4 + wid) * 4 + s) * 64 + lane) * 8);

    f32x4 c2[8];
    #pragma unroll
    for (int t = 0; t < 8; ++t) c2[t] = (f32x4){0.f, 0.f, 0.f, 0.f};

    #pragma unroll
    for (int half = 0; half < 2; ++half) {
        for (int tt = 0; tt < 8; ++tt) {
            int t = half * 8 + tt;
            f32x4 acc = {0.f, 0.f, 0.f, 0.f};
            #pragma unroll
            for (int s = 0; s < 4; ++s) {
                s16x8 bf = *(const s16x8*)(w1p + ((size_t)(t * 4 + s) * 64 + lane) * 8);
                acc = __builtin_amdgcn_mfma_f32_16x16x32_bf16(af[s], bf, acc, 0, 0, 0);
            }
            float b1v = b1[t * 16 + colb];
            #pragma unroll
            for (int r = 0; r < 4; ++r)
                sC1[wid][(r0 + r) * 136 + tt * 16 + colb] = f2bf(fmaxf(acc[r] + b1v, 0.f));
        }
        s16x8 a2h[4];
        #pragma unroll
        for (int s = 0; s < 4; ++s)
            a2h[s] = *(const s16x8*)&sC1[wid][arow * 136 + s * 32 + aq];
        for (int t = 0; t < 8; ++t) {
            #pragma unroll
            for (int s = 0; s < 4; ++s) {
                s16x8 bf = *(const s16x8*)(w2p + ((size_t)(t * 8 + half * 4 + s) * 64 + lane) * 8);
                c2[t] = __builtin_amdgcn_mfma_f32_16x16x32_bf16(a2h[s], bf, c2[t], 0, 0, 0);
            }
        }
    }

    s16x8 af3[3];
    #pragma unroll
    for (int s = 0; s < 3; ++s)
        af3[s] = *(const s16x8*)(f_t + ((((size_t)rb * 4 + wid) * 3 + s) * 64 + lane) * 8);

    {
        float b2v[8];
        #pragma unroll
        for (int t = 0; t < 8; ++t) b2v[t] = b2[t * 16 + colb];
        #pragma unroll
        for (int t = 0; t < 8; ++t)
            #pragma unroll
            for (int r = 0; r < 4; ++r) c2[t][r] += b2v[t];
    }
    float mu4[4], rs4[4];
    #pragma unroll
    for (int r = 0; r < 4; ++r) {
        float s = 0.f, ss = 0.f;
        #pragma unroll
        for (int t = 0; t < 8; ++t) { float x = c2[t][r]; s += x; ss += x * x; }
        #pragma unroll
        for (int m = 1; m < 16; m <<= 1) {
            s  += __shfl_xor(s, m);
            ss += __shfl_xor(ss, m);
        }
        float mu = s * (1.f / 128.f);
        float var = ss * (1.f / 128.f) - mu * mu;
        mu4[r] = mu;
        rs4[r] = rsqrtf(var + 1e-5f);
    }
    int growb = rb * 64 + wid * 16 + r0;
    #pragma unroll
    for (int t = 0; t < 8; ++t) {
        f32x4 racc = {0.f, 0.f, 0.f, 0.f};
        #pragma unroll
        for (int s = 0; s < 3; ++s) {
            s16x8 bf = *(const s16x8*)(gp + ((size_t)(t * 3 + s) * 64 + lane) * 8);
            racc = __builtin_amdgcn_mfma_f32_16x16x32_bf16(af3[s], bf, racc, 0, 0, 0);
        }
        int n = t * 16 + colb;
        float gv = g[n], btv = bt[n];
        #pragma unroll
        for (int r = 0; r < 4; ++r) {
            int grow = growb + r;
            if (grow < NHALF) {
                float y = (c2[t][r] - mu4[r]) * rs4[r] * gv + btv;
                float o = fmaxf(y * inv_sqrt_n, 0.f) + racc[r];
                if (l < 7) {
                    outb[(size_t)grow * DD + n] = f2bf(o);
                } else {
                    edge_out[(size_t)(2 * grow) * DD + n] = o;
                    edge_out[(size_t)(2 * grow + 1) * DD + n] = o;
                }
            }
        }
    }
}

// ================= standalone gather: one wave per dst row =================
template<bool L0>
__global__ __launch_bounds__(256) void k_gather(
    const uint_t* __restrict__ node2, const uint_t* __restrict__ half2,
    const int* __restrict__ rp, const int* __restrict__ psrc,
    const int* __restrict__ peid, uint_t* __restrict__ agg)
{
    int wid = threadIdx.x >> 6, lane = threadIdx.x & 63;
    int n = blockIdx.x * 4 + wid;
    if (n >= 30016) return;
    float v0 = 0.f, v1 = 0.f;
    if (n < NA) {
        int p0 = rp[n], p1 = rp[n + 1];
        for (int pb = p0; pb < p1; pb += 64) {
            int cnt = min(p1 - pb, 64);
            int sv = 0, ev = 0;
            if (lane < cnt) {
                sv = psrc[pb + lane];
                if (!L0) ev = peid[pb + lane] >> 1;
            }
            for (int i = 0; i < cnt; i += 4) {
                bool c1 = (i + 1 < cnt), c2m = (i + 2 < cnt), c3 = (i + 3 < cnt);
                int s0 = __shfl(sv, i);
                int s1 = __shfl(sv, c1 ? i + 1 : i);
                int s2 = __shfl(sv, c2m ? i + 2 : i);
                int s3 = __shfl(sv, c3 ? i + 3 : i);
                uint_t a0 = node2[(size_t)s0 * 64 + lane];
                uint_t a1 = node2[(size_t)s1 * 64 + lane];
                uint_t a2 = node2[(size_t)s2 * 64 + lane];
                uint_t a3 = node2[(size_t)s3 * 64 + lane];
                uint_t h0 = 0, h1 = 0, h2 = 0, h3 = 0;
                if (!L0) {
                    int e0 = __shfl(ev, i);
                    int e1 = __shfl(ev, c1 ? i + 1 : i);
                    int e2 = __shfl(ev, c2m ? i + 2 : i);
                    int e3 = __shfl(ev, c3 ? i + 3 : i);
                    h0 = half2[(size_t)e0 * 64 + lane];
                    h1 = half2[(size_t)e1 * 64 + lane];
                    h2 = half2[(size_t)e2 * 64 + lane];
                    h3 = half2[(size_t)e3 * 64 + lane];
                }
                v0 += bf2f((ushort_t)(a0 & 0xffff));
                v1 += bf2f((ushort_t)(a0 >> 16));
                if (!L0) { v0 += bf2f((ushort_t)(h0 & 0xffff)); v1 += bf2f((ushort_t)(h0 >> 16)); }
                if (c1) {
                    v0 += bf2f((ushort_t)(a1 & 0xffff));
                    v1 += bf2f((ushort_t)(a1 >> 16));
                    if (!L0) { v0 += bf2f((ushort_t)(h1 & 0xffff)); v1 += bf2f((ushort_t)(h1 >> 16)); }
                }
                if (c2m) {
                    v0 += bf2f((ushort_t)(a2 & 0xffff));
                    v1 += bf2f((ushort_t)(a2 >> 16));
                    if (!L0) { v0 += bf2f((ushort_t)(h2 & 0xffff)); v1 += bf2f((ushort_t)(h2 >> 16)); }
                }
                if (c3) {
                    v0 += bf2f((ushort_t)(a3 & 0xffff));
                    v1 += bf2f((ushort_t)(a3 >> 16));
                    if (!L0) { v0 += bf2f((ushort_t)(h3 & 0xffff)); v1 += bf2f((ushort_t)(h3 >> 16)); }
                }
            }
        }
    }
    agg[(size_t)n * 64 + lane] = (uint_t)f2bf(v0) | ((uint_t)f2bf(v1) << 16);
}

// ================= MLP only (ab path) — round-3 monolithic body, barrier removed ======
// sC1 slices are wave-private ([wid] on both sides) -> __syncthreads unnecessary
template<int KS, bool L0>
__global__ __launch_bounds__(256) void k_mlp_ab(
    const ushort_t* __restrict__ agg, const ushort_t* __restrict__ fab_t,
    const ushort_t* __restrict__ w1p, const float* __restrict__ b1,
    const ushort_t* __restrict__ w2p, const float* __restrict__ b2,
    const float* __restrict__ g, const float* __restrict__ bt,
    const float* __restrict__ resid, float* __restrict__ outf,
    ushort_t* __restrict__ outb, float inv_sqrt_n)
{
    __shared__ ushort_t sC1[4][16 * 264];
    int tid = threadIdx.x, wid = tid >> 6, lane = tid & 63;
    int g0 = blockIdx.x * 64 + wid * 16;

    int arow = lane & 15, aq = (lane >> 4) << 3;
    s16x8 af[KS];
    #pragma unroll
    for (int s = 0; s < 4; ++s)
        af[s] = *(const s16x8*)(agg + (size_t)(g0 + arow) * 128 + s * 32 + aq);
    if (L0) {
        #pragma unroll
        for (int s = 0; s < 3; ++s)
            af[4 + s] = *(const s16x8*)(fab_t + ((((size_t)blockIdx.x * 4 + wid) * 3 + s) * 64 + lane) * 8);
    }

    for (int t = 0; t < 16; ++t) {
        f32x4 acc = {0.f, 0.f, 0.f, 0.f};
        #pragma unroll
        for (int s = 0; s < KS; ++s) {
            s16x8 bf = *(const s16x8*)(w1p + ((size_t)(t * KS + s) * 64 + lane) * 8);
            acc = __builtin_amdgcn_mfma_f32_16x16x32_bf16(af[s], bf, acc, 0, 0, 0);
        }
        int n = t * 16 + (lane & 15);
        float b1v = b1[n];
        int r0 = (lane >> 4) << 2;
        #pragma unroll
        for (int r = 0; r < 4; ++r)
            sC1[wid][(r0 + r) * 264 + n] = f2bf(fmaxf(acc[r] + b1v, 0.f));
    }

    s16x8 a2[8];
    #pragma unroll
    for (int s = 0; s < 8; ++s) a2[s] = *(const s16x8*)&sC1[wid][arow * 264 + s * 32 + aq];
    f32x4 c2[8];
    for (int t = 0; t < 8; ++t) {
        f32x4 acc = {0.f, 0.f, 0.f, 0.f};
        #pragma unroll
        for (int s = 0; s < 8; ++s) {
            s16x8 bf = *(const s16x8*)(w2p + ((size_t)(t * 8 + s) * 64 + lane) * 8);
            acc = __builtin_amdgcn_mfma_f32_16x16x32_bf16(a2[s], bf, acc, 0, 0, 0);
        }
        c2[t] = acc;
    }

    int colb = lane & 15;
    float b2v[8], gv[8], btv[8];
    #pragma unroll
    for (int t = 0; t < 8; ++t) {
        int n = t * 16 + colb;
        b2v[t] = b2[n]; gv[t] = g[n]; btv[t] = bt[n];
    }
    #pragma unroll
    for (int t = 0; t < 8; ++t)
        #pragma unroll
        for (int r = 0; r < 4; ++r) c2[t][r] += b2v[t];

    int r0 = (lane >> 4) << 2;
    #pragma unroll
    for (int r = 0; r < 4; ++r) {
        float s = 0.f, ss = 0.f;
        #pragma unroll
        for (int t = 0; t < 8; ++t) { float x = c2[t][r]; s += x; ss += x * x; }
        #pragma unroll
        for (int m = 1; m < 16; m <<= 1) {
            s  += __shfl_xor(s, m);
            ss += __shfl_xor(ss, m);
        }
        float mu = s * (1.f / 128.f);
        float var = ss * (1.f / 128.f) - mu * mu;
        float rstd = rsqrtf(var + 1e-5f);
        int grow = g0 + r0 + r;
        if (grow < NA) {
            #pragma unroll
            for (int t = 0; t < 8; ++t) {
                int n = t * 16 + colb;
                float y = (c2[t][r] - mu) * rstd * gv[t] + btv[t];
                float o = fmaxf(y * inv_sqrt_n, 0.f) + resid[(size_t)grow * DD + n];
                outf[(size_t)grow * DD + n] = o;
                outb[(size_t)grow * DD + n] = f2bf(o);
            }
        }
    }
}

// ---------------- graph = node.mean(axis=0)
__global__ __launch_bounds__(256) void k_graph_mean(
    const float* __restrict__ node, float* __restrict__ graph)
{
    int tid = threadIdx.x;
    int c = tid & 127, h = tid >> 7;
    const int rpb = 250;
    int r0 = blockIdx.x * rpb;
    float s = 0.f;
    for (int r = r0 + h; r < r0 + rpb; r += 2) s += node[(size_t)r * DD + c];
    __shared__ float sS[256];
    sS[tid] = s;
    __syncthreads();
    if (tid < 128) atomicAdd(&graph[c], (sS[tid] + sS[tid + 128]) * (1.f / 30000.f));
}

extern "C" void kernel_launch(void* const* d_in, const int* in_sizes, int n_in,
                              void* d_out, int out_size, void* d_ws, size_t ws_size,
                              hipStream_t stream)
{
    const int*   atom_cat         = (const int*)d_in[0];
    const int*   bond_cat         = (const int*)d_in[1];
    const float* bond_float       = (const float*)d_in[2];
    const float* angle_float      = (const float*)d_in[3];
    const int*   ab_src           = (const int*)d_in[4];
    const int*   ab_dst           = (const int*)d_in[5];
    const int*   ba_src           = (const int*)d_in[6];
    const int*   ba_dst           = (const int*)d_in[7];
    const float* atom_emb         = (const float*)d_in[8];
    const float* bond_emb_init    = (const float*)d_in[9];
    const float* bond_rbf_w_init  = (const float*)d_in[10];
    const float* bond_rbf_b_init  = (const float*)d_in[11];
    const float* layer_bond_emb   = (const float*)d_in[12];
    const float* layer_bond_rbf_w = (const float*)d_in[13];
    const float* layer_bond_rbf_b = (const float*)d_in[14];
    const float* layer_angle_rbf_w= (const float*)d_in[15];
    const float* layer_angle_rbf_b= (const float*)d_in[16];
    const float* ab_w1 = (const float*)d_in[17];
    const float* ab_b1 = (const float*)d_in[18];
    const float* ab_w2 = (const float*)d_in[19];
    const float* ab_b2 = (const float*)d_in[20];
    const float* ab_g  = (const float*)d_in[21];
    const float* ab_bt = (const float*)d_in[22];
    const float* ba_w1 = (const float*)d_in[23];
    const float* ba_b1 = (const float*)d_in[24];
    const float* ba_w2 = (const float*)d_in[25];
    const float* ba_b2 = (const float*)d_in[26];
    const float* ba_g  = (const float*)d_in[27];
    const float* ba_bt = (const float*)d_in[28];

    float* node     = (float*)d_out;
    float* edge_out = node + (size_t)NA * DD;
    float* graph    = edge_out + (size_t)NB * DD;

    // ---- ws layout
    ushort_t* nbf0   = (ushort_t*)d_ws;                        // NA*128
    ushort_t* nbf1   = nbf0 + (size_t)NA * DD;                 // NA*128
    ushort_t* pool   = nbf1 + (size_t)NA * DD;                 // 4*NHALF*128
    ushort_t* aext_t = pool + (size_t)4 * NHALF * DD;          // 782*8192
    ushort_t* f_t    = aext_t + (size_t)782 * 8192;            // 782*6144
    ushort_t* fab_t  = f_t + (size_t)782 * 6144;               // 469*6144
    ushort_t* wp     = fab_t + (size_t)469 * 6144;             // 146432*8
    float*    W1ext  = (float*)(wp + (size_t)146432 * 8);      // 262144
    float*    W1ab0x = W1ext + 262144;                         // 24576
    int*      cur_ab = (int*)(W1ab0x + 24576);                 // NA
    int*      cur_ba = cur_ab + NA;                            // NHALF
    int*      rp_ab  = cur_ba + NHALF;                         // NA+1
    int*      rp_ba  = rp_ab + NA + 1;                         // NHALF+1
    int*      psrc_ab= rp_ba + NHALF + 1;                      // NB
    int*      peid_ab= psrc_ab + NB;                           // NB
    int*      psrc_ba= peid_ab + NB;                           // NANG
    float*    pang   = (float*)(psrc_ba + NANG);               // NANG
    uint_t*   agg    = (uint_t*)(pang + NANG);                 // 30016*64

    const float isn_a = (float)(1.0 / sqrt(30000.0));
    const float isn_h = (float)(1.0 / sqrt(50000.0));

    // ---- CSR build
    hipMemsetAsync(cur_ab, 0, (size_t)(NA + NHALF) * sizeof(int), stream);
    k_hist2<<<(NB + NANG + 255) / 256, 256, 0, stream>>>(ab_dst, cur_ab, ba_dst, cur_ba);
    k_scan<<<2, 1024, 0, stream>>>(cur_ab, rp_ab, cur_ba, rp_ba);
    k_fill_ab<<<(NB + 255) / 256, 256, 0, stream>>>(ab_src, ab_dst, cur_ab, psrc_ab, peid_ab);
    k_fill_ba<<<(NANG + 255) / 256, 256, 0, stream>>>(ba_src, ba_dst, angle_float, cur_ba, psrc_ba, pang);

    // ---- features + folds + packing
    k_feat_ba<<<782, 256, 0, stream>>>(rp_ba, psrc_ba, pang, bond_float, bond_cat, aext_t, f_t);
    k_feat_ab<<<469, 256, 0, stream>>>(rp_ab, peid_ab, bond_float, bond_cat, fab_t);
    k_fold<<<1120, 256, 0, stream>>>(ba_w1, layer_bond_emb, layer_bond_rbf_w,
        layer_bond_rbf_b, layer_angle_rbf_w, layer_angle_rbf_b,
        ab_w1, bond_emb_init, bond_rbf_w_init, bond_rbf_b_init, W1ext, W1ab0x);
    k_pack<<<572, 256, 0, stream>>>(ab_w1, W1ab0x, W1ext, ab_w2, ba_w2,
        layer_bond_emb, layer_bond_rbf_w, layer_bond_rbf_b, wp);

    k_node_init<<<NA / 2, 256, 0, stream>>>(atom_cat, atom_emb, node, nbf0);

    // ---- batched ba layers 0-3 -> pool[0..3]
    k_ba_batch<<<782 * 4, 256, 0, stream>>>(aext_t, f_t, wp, ba_b1, ba_b2, ba_g, ba_bt,
        pool, edge_out, 0, isn_h);

    ushort_t* nbf[2] = {nbf0, nbf1};
    for (int l = 0; l < LL; ++l) {
        const uint_t* rd = (const uint_t*)nbf[l & 1];
        ushort_t* wr = nbf[1 - (l & 1)];
        const uint_t* halfbuf = (const uint_t*)(pool + (size_t)((l - 1) & 3) * NHALF * DD);
        const ushort_t* ab_w1p = l ? wp + ((size_t)7168 + (size_t)(l - 1) * 4096) * 8 : wp;
        const ushort_t* ab_w2p = wp + ((size_t)68608 + (size_t)l * 4096) * 8;

        if (l == 0) {
            k_gather<true><<<7504, 256, 0, stream>>>(rd, rd, rp_ab, psrc_ab, peid_ab, agg);
            k_mlp_ab<7, true><<<469, 256, 0, stream>>>(
                (const ushort_t*)agg, fab_t,
                ab_w1p, ab_b1, ab_w2p, ab_b2, ab_g, ab_bt,
                node, node, wr, isn_a);
        } else {
            k_gather<false><<<7504, 256, 0, stream>>>(rd, halfbuf, rp_ab, psrc_ab, peid_ab, agg);
            k_mlp_ab<4, false><<<469, 256, 0, stream>>>(
                (const ushort_t*)agg, fab_t,
                ab_w1p, ab_b1 + l * HH, ab_w2p, ab_b2 + l * DD,
                ab_g + l * DD, ab_bt + l * DD, node, node, wr, isn_a);
        }

        if (l == 3)   // pool[0..2] consumed; refill with layers 4-6 (+edge from 7)
            k_ba_batch<<<782 * 4, 256, 0, stream>>>(aext_t, f_t, wp, ba_b1, ba_b2, ba_g, ba_bt,
                pool, edge_out, 4, isn_h);
    }

    hipMemsetAsync(graph, 0, DD * sizeof(float), stream);
    k_graph_mean<<<120, 256, 0, stream>>>(node, graph);
}